// Round 2
// baseline (1123.215 us; speedup 1.0000x reference)
//
#include <hip/hip_runtime.h>
#include <math.h>

// Shapes (fixed by the problem)
#define NB   256
#define NR   36
#define NL   60
#define DIMG 2048
#define DWRD 300
#define DEMB 1024

// ------------------------------------------------------------------
// Tiled fp32 SGEMM: C[M,N] = A[M,K] @ B[K,N] + bias[N]
// BM=BN=128, BK=16, 256 threads, 8x8 per thread. K guarded (K=300 case).
// M, N are multiples of 128 for all our calls.
// ------------------------------------------------------------------
__global__ __launch_bounds__(256)
void sgemm_bias(const float* __restrict__ A, const float* __restrict__ Bm,
                const float* __restrict__ bias, float* __restrict__ C,
                int M, int N, int K)
{
    __shared__ float As[16][136];   // transposed: As[k][m], +8 pad
    __shared__ float Bs[16][136];   // Bs[k][n], +8 pad

    const int tid = threadIdx.x;
    const int tx  = tid & 15;       // 0..15 -> n sub-tile
    const int ty  = tid >> 4;       // 0..15 -> m sub-tile
    const int row0 = blockIdx.y * 128;
    const int col0 = blockIdx.x * 128;

    // A loader: float4 slots tid and tid+256 over 128x16 tile
    const int ar = tid >> 2;            // 0..63
    const int ac = (tid & 3) << 2;      // 0,4,8,12
    // B loader: float4 slots over 16x128 tile
    const int br = tid >> 5;            // 0..7
    const int bc = (tid & 31) << 2;     // 0..124

    float acc[8][8];
    #pragma unroll
    for (int i = 0; i < 8; ++i)
        #pragma unroll
        for (int j = 0; j < 8; ++j) acc[i][j] = 0.f;

    for (int k0 = 0; k0 < K; k0 += 16) {
        __syncthreads();
        #pragma unroll
        for (int h = 0; h < 2; ++h) {
            const int r = ar + h * 64;
            const float* src = A + (size_t)(row0 + r) * K + k0 + ac;
            float4 v;
            if (k0 + ac + 4 <= K) {
                v = *reinterpret_cast<const float4*>(src);
            } else {
                v.x = (k0 + ac + 0 < K) ? src[0] : 0.f;
                v.y = (k0 + ac + 1 < K) ? src[1] : 0.f;
                v.z = (k0 + ac + 2 < K) ? src[2] : 0.f;
                v.w = (k0 + ac + 3 < K) ? src[3] : 0.f;
            }
            As[ac + 0][r] = v.x; As[ac + 1][r] = v.y;
            As[ac + 2][r] = v.z; As[ac + 3][r] = v.w;
        }
        #pragma unroll
        for (int h = 0; h < 2; ++h) {
            const int r = br + h * 8;
            float4 v = make_float4(0.f, 0.f, 0.f, 0.f);
            if (k0 + r < K)
                v = *reinterpret_cast<const float4*>(Bm + (size_t)(k0 + r) * N + col0 + bc);
            *reinterpret_cast<float4*>(&Bs[r][bc]) = v;
        }
        __syncthreads();
        #pragma unroll
        for (int kk = 0; kk < 16; ++kk) {
            float a[8], b[8];
            *reinterpret_cast<float4*>(&a[0]) = *reinterpret_cast<const float4*>(&As[kk][ty * 8]);
            *reinterpret_cast<float4*>(&a[4]) = *reinterpret_cast<const float4*>(&As[kk][ty * 8 + 4]);
            *reinterpret_cast<float4*>(&b[0]) = *reinterpret_cast<const float4*>(&Bs[kk][tx * 8]);
            *reinterpret_cast<float4*>(&b[4]) = *reinterpret_cast<const float4*>(&Bs[kk][tx * 8 + 4]);
            #pragma unroll
            for (int i = 0; i < 8; ++i)
                #pragma unroll
                for (int j = 0; j < 8; ++j)
                    acc[i][j] = fmaf(a[i], b[j], acc[i][j]);
        }
    }

    float bv[8];
    *reinterpret_cast<float4*>(&bv[0]) = *reinterpret_cast<const float4*>(bias + col0 + tx * 8);
    *reinterpret_cast<float4*>(&bv[4]) = *reinterpret_cast<const float4*>(bias + col0 + tx * 8 + 4);
    #pragma unroll
    for (int i = 0; i < 8; ++i) {
        float* dst = C + (size_t)(row0 + ty * 8 + i) * N + col0 + tx * 8;
        float4 o0 = make_float4(acc[i][0] + bv[0], acc[i][1] + bv[1],
                                acc[i][2] + bv[2], acc[i][3] + bv[3]);
        float4 o1 = make_float4(acc[i][4] + bv[4], acc[i][5] + bv[5],
                                acc[i][6] + bv[6], acc[i][7] + bv[7]);
        *reinterpret_cast<float4*>(dst)     = o0;
        *reinterpret_cast<float4*>(dst + 4) = o1;
    }
}

// ------------------------------------------------------------------
// Row-wise l2 normalization, row length 1024. One block (256 thr) per row.
// x <- x * rsqrt(sum(x^2) + 1e-12)
// ------------------------------------------------------------------
__global__ __launch_bounds__(256)
void l2norm_rows(float* __restrict__ X)
{
    __shared__ float red[4];
    const int tid = threadIdx.x;
    float4* p = reinterpret_cast<float4*>(X + (size_t)blockIdx.x * DEMB);
    float4 v = p[tid];
    float ss = v.x * v.x + v.y * v.y + v.z * v.z + v.w * v.w;
    #pragma unroll
    for (int o = 32; o; o >>= 1) ss += __shfl_xor(ss, o);
    if ((tid & 63) == 0) red[tid >> 6] = ss;
    __syncthreads();
    const float sc = rsqrtf(red[0] + red[1] + red[2] + red[3] + 1e-12f);
    v.x *= sc; v.y *= sc; v.z *= sc; v.w *= sc;
    p[tid] = v;
}

// ------------------------------------------------------------------
// Per-batch cross attention + cosine similarity + masked mean.
// One block (4 waves) per batch. Wave w owns words l = w, w+4, ...
// Phase 1: sim[l][r] via r-chunks of 12 img rows staged in LDS (48KB).
// Phase 2: e[l][r] = exp(9*(sim - rowmax)) (softmax denom cancels in cosine).
// Phase 3: att/num/||att|| via d-chunks of 256 (36KB, same LDS buffer).
// ------------------------------------------------------------------
__device__ __forceinline__ float wred(float v)
{
    #pragma unroll
    for (int o = 32; o; o >>= 1) v += __shfl_xor(v, o);
    return v;
}

__global__ __launch_bounds__(256)
void scan_attention(const float* __restrict__ img, const float* __restrict__ cap,
                    const int* __restrict__ lens, float* __restrict__ out)
{
    __shared__ float simg[12 * 1024];        // 48KB: 12x1024 (p1) or 36x256 (p3)
    __shared__ float swt[NL][NR + 1];        // sim scores, then e-weights
    __shared__ float accv[3][NL];            // 0: ||cap||^2, 1: num, 2: ||att||^2
    __shared__ float wsum[4];

    const int b    = blockIdx.x;
    const int tid  = threadIdx.x;
    const int w    = tid >> 6;
    const int lane = tid & 63;
    const int len  = lens[b];
    const float* imgb = img + (size_t)b * NR * DEMB;
    const float* capb = cap + (size_t)b * NL * DEMB;

    // ---- Phase 1: similarity scores ----
    for (int rc = 0; rc < 3; ++rc) {
        __syncthreads();
        {   // stage 12 rows x 1024 = 3072 float4
            const float4* src = reinterpret_cast<const float4*>(imgb + (size_t)rc * 12 * DEMB);
            float4* dst = reinterpret_cast<float4*>(simg);
            #pragma unroll
            for (int t = 0; t < 12; ++t) dst[tid + t * 256] = src[tid + t * 256];
        }
        __syncthreads();
        for (int i = 0; i < 15; ++i) {
            const int l = w + i * 4;
            float c[16];
            #pragma unroll
            for (int j = 0; j < 16; ++j) c[j] = capb[(size_t)l * DEMB + j * 64 + lane];
            if (rc == 0) {
                float s2 = 0.f;
                #pragma unroll
                for (int j = 0; j < 16; ++j) s2 = fmaf(c[j], c[j], s2);
                s2 = wred(s2);
                if (lane == 0) accv[0][l] = s2;
            }
            for (int r = 0; r < 12; ++r) {
                float p = 0.f;
                #pragma unroll
                for (int j = 0; j < 16; ++j)
                    p = fmaf(c[j], simg[r * 1024 + j * 64 + lane], p);
                p = wred(p);
                if (lane == 0) swt[l][rc * 12 + r] = p;
            }
        }
    }

    // ---- Phase 2: unnormalized softmax weights (within-wave only) ----
    for (int i = 0; i < 15; ++i) {
        const int l = w + i * 4;
        float m = -1e30f;
        for (int r = 0; r < NR; ++r) m = fmaxf(m, swt[l][r]);
        float e = 0.f;
        if (lane < NR) e = __expf(9.f * (swt[l][lane] - m));
        // all lanes finished reading swt[l][*] (wave lockstep) before writes
        if (lane < NR) swt[l][lane] = e;
    }

    // ---- Phase 3: att, num, ||att||^2 over d-chunks of 256 ----
    for (int dc = 0; dc < 4; ++dc) {
        __syncthreads();
        {   // stage 36 rows x 256 = 2304 float4
            float4* dst = reinterpret_cast<float4*>(simg);
            #pragma unroll
            for (int t = 0; t < 9; ++t) {
                const int f  = tid + t * 256;
                const int r  = f >> 6;
                const int c4 = f & 63;
                dst[f] = *reinterpret_cast<const float4*>(
                    imgb + (size_t)r * DEMB + dc * 256 + c4 * 4);
            }
        }
        __syncthreads();
        for (int i = 0; i < 15; ++i) {
            const int l = w + i * 4;
            float cj[4];
            #pragma unroll
            for (int j = 0; j < 4; ++j)
                cj[j] = capb[(size_t)l * DEMB + dc * 256 + j * 64 + lane];
            float np = 0.f, ap = 0.f;
            #pragma unroll
            for (int j = 0; j < 4; ++j) {
                float a = 0.f;
                #pragma unroll
                for (int r = 0; r < NR; ++r)
                    a = fmaf(swt[l][r], simg[r * 256 + j * 64 + lane], a);
                np = fmaf(cj[j], a, np);
                ap = fmaf(a, a, ap);
            }
            np = wred(np);
            ap = wred(ap);
            if (lane == 0) {
                if (dc == 0) { accv[1][l] = np;  accv[2][l] = ap; }
                else         { accv[1][l] += np; accv[2][l] += ap; }
            }
        }
    }

    // ---- Finalize: cosine sim, mask, mean ----
    if (lane == 0) {
        float wacc = 0.f;
        for (int i = 0; i < 15; ++i) {
            const int l = w + i * 4;
            if (l < len) {
                const float ncap = fmaxf(sqrtf(accv[0][l]), 1e-8f);
                const float natt = fmaxf(sqrtf(accv[2][l]), 1e-8f);
                wacc += accv[1][l] / (ncap * natt);
            }
        }
        wsum[w] = wacc;
    }
    __syncthreads();
    if (tid == 0)
        out[b] = (wsum[0] + wsum[1] + wsum[2] + wsum[3]) / (float)len;
}

// ------------------------------------------------------------------
extern "C" void kernel_launch(void* const* d_in, const int* in_sizes, int n_in,
                              void* d_out, int out_size, void* d_ws, size_t ws_size,
                              hipStream_t stream)
{
    const float* images   = (const float*)d_in[0];   // (256,36,2048)
    const float* captions = (const float*)d_in[1];   // (256,60,300)
    const int*   lens     = (const int*)  d_in[2];   // (256,)
    const float* W_img    = (const float*)d_in[3];   // (2048,1024)
    const float* b_img    = (const float*)d_in[4];   // (1024,)
    const float* W_txt    = (const float*)d_in[5];   // (300,1024)
    const float* b_txt    = (const float*)d_in[6];   // (1024,)
    float*       out      = (float*)d_out;           // (256,)

    float* img_embs = (float*)d_ws;                        // 9216 x 1024
    float* cap_embs = img_embs + (size_t)NB * NR * DEMB;   // 15360 x 1024
    // workspace need: (9216 + 15360) * 1024 * 4 B = 96 MiB

    // Encoder GEMMs (+bias)
    sgemm_bias<<<dim3(DEMB / 128, (NB * NR) / 128), 256, 0, stream>>>(
        images, W_img, b_img, img_embs, NB * NR, DEMB, DIMG);
    sgemm_bias<<<dim3(DEMB / 128, (NB * NL) / 128), 256, 0, stream>>>(
        captions, W_txt, b_txt, cap_embs, NB * NL, DEMB, DWRD);

    // L2 normalization
    l2norm_rows<<<NB * NR, 256, 0, stream>>>(img_embs);
    l2norm_rows<<<NB * NL, 256, 0, stream>>>(cap_embs);

    // Cross attention + cosine + masked mean
    scan_attention<<<NB, 256, 0, stream>>>(img_embs, cap_embs, lens, out);
}

// Round 3
// 657.996 us; speedup vs baseline: 1.7070x; 1.7070x over previous
//
#include <hip/hip_runtime.h>
#include <math.h>

// Shapes (fixed by the problem)
#define NB   256
#define NR   36
#define NL   60
#define DIMG 2048
#define DWRD 300
#define DEMB 1024

typedef __attribute__((ext_vector_type(8))) short short8;
typedef __attribute__((ext_vector_type(4))) short short4v;
typedef __attribute__((ext_vector_type(4))) float f32x4;

#define AS1 __attribute__((address_space(1)))
#define AS3 __attribute__((address_space(3)))

__device__ __forceinline__ unsigned short bf16_rne(float x) {
    unsigned u = __builtin_bit_cast(unsigned, x);
    unsigned r = u + 0x7FFFu + ((u >> 16) & 1u);
    return (unsigned short)(r >> 16);
}
__device__ __forceinline__ float bf16_to_f(unsigned short h) {
    unsigned u = ((unsigned)h) << 16;
    return __builtin_bit_cast(float, u);
}

// ==================================================================
// FAST PATH (bf16 split-precision MFMA)
// ==================================================================

// W (K x N f32, row-major) -> Wt_hi/Wt_lo (N x KP bf16), zero-padded k>=K.
// 64x64 tiles via LDS. Grid: (KP/64, N/64).
__global__ __launch_bounds__(256)
void split_transpose(const float* __restrict__ W, short* __restrict__ Thi,
                     short* __restrict__ Tlo, int K, int N, int KP)
{
    __shared__ float T[64][68];
    const int t = threadIdx.x;
    const int k0 = blockIdx.x * 64, n0 = blockIdx.y * 64;
    #pragma unroll
    for (int q = 0; q < 4; ++q) {
        const int r = (t >> 4) + q * 16;        // k-local
        const int c4 = (t & 15) * 4;            // n-local
        float4 v = make_float4(0.f, 0.f, 0.f, 0.f);
        if (k0 + r < K)
            v = *reinterpret_cast<const float4*>(W + (size_t)(k0 + r) * N + n0 + c4);
        T[r][c4] = v.x; T[r][c4 + 1] = v.y; T[r][c4 + 2] = v.z; T[r][c4 + 3] = v.w;
    }
    __syncthreads();
    #pragma unroll
    for (int q = 0; q < 4; ++q) {
        const int nl = (t >> 4) + q * 16;       // n-local
        const int kc = (t & 15) * 4;            // k-local
        short hs[4] __attribute__((aligned(8)));
        short ls[4] __attribute__((aligned(8)));
        #pragma unroll
        for (int i = 0; i < 4; ++i) {
            const float x = T[kc + i][nl];
            const unsigned short hb = bf16_rne(x);
            hs[i] = (short)hb;
            ls[i] = (short)bf16_rne(x - bf16_to_f(hb));
        }
        const size_t o = (size_t)(n0 + nl) * KP + k0 + kc;
        *reinterpret_cast<short4v*>(Thi + o) = *reinterpret_cast<short4v*>(hs);
        *reinterpret_cast<short4v*>(Tlo + o) = *reinterpret_cast<short4v*>(ls);
    }
}

// C[M,N] = A[M,K](f32) @ B[K,N] + bias, where B is given split/transposed:
// Bt_hi/Bt_lo (N x KP bf16). A is split to hi/lo on the fly per k-tile.
// acc += Ahi*Bhi + Alo*Bhi + Ahi*Blo  (drops lo*lo, ~2^-18 relative).
// 128x128 tile, BK=32, 256 threads (4 waves, each 64x64 output).
__global__ __launch_bounds__(256)
void gemm_asplit(const float* __restrict__ A, const short* __restrict__ Bthi,
                 const short* __restrict__ Btlo, const float* __restrict__ bias,
                 float* __restrict__ C, int M, int N, int K, int KP)
{
    __shared__ short Ahi[128 * 32], Alo[128 * 32];
    __shared__ short Bhi[128 * 32], Blo[128 * 32];

    const int tid  = threadIdx.x;
    const int w    = tid >> 6, lane = tid & 63;
    const int wr   = w >> 1,   wc   = w & 1;
    const int row0 = blockIdx.y * 128, col0 = blockIdx.x * 128;

    f32x4 acc[4][4];
    #pragma unroll
    for (int m = 0; m < 4; ++m)
        #pragma unroll
        for (int n = 0; n < 4; ++n)
            acc[m][n] = (f32x4){0.f, 0.f, 0.f, 0.f};

    for (int k0 = 0; k0 < KP; k0 += 32) {
        __syncthreads();   // previous tile's compute done
        // ---- stage A: f32 -> hi/lo bf16 (2x 16B chunks per thread) ----
        #pragma unroll
        for (int h = 0; h < 2; ++h) {
            const int c = tid + h * 256;            // chunk 0..511
            const int r = c >> 2;                   // row 0..127
            const int ke = (c & 3) * 8;             // k 0..24
            const int gk = k0 + ke;
            const float* src = A + (size_t)(row0 + r) * K + gk;
            float v[8] __attribute__((aligned(16)));
            if (gk + 8 <= K) {
                *reinterpret_cast<float4*>(&v[0]) = *reinterpret_cast<const float4*>(src);
                *reinterpret_cast<float4*>(&v[4]) = *reinterpret_cast<const float4*>(src + 4);
            } else {
                #pragma unroll
                for (int i = 0; i < 8; ++i)
                    v[i] = (gk + i < K) ? src[i] : 0.f;
            }
            short hs[8] __attribute__((aligned(16)));
            short ls[8] __attribute__((aligned(16)));
            #pragma unroll
            for (int i = 0; i < 8; ++i) {
                const unsigned short hb = bf16_rne(v[i]);
                hs[i] = (short)hb;
                ls[i] = (short)bf16_rne(v[i] - bf16_to_f(hb));
            }
            *reinterpret_cast<short8*>(&Ahi[c * 8]) = *reinterpret_cast<short8*>(hs);
            *reinterpret_cast<short8*>(&Alo[c * 8]) = *reinterpret_cast<short8*>(ls);
        }
        // ---- stage B: global_load_lds 16B, linear (2 slots/wave/matrix) ----
        #pragma unroll
        for (int j = 0; j < 2; ++j) {
            const int s = w * 2 + j;                 // slot 0..7 (16 n-rows each)
            const int n = 16 * s + (lane >> 2);
            const size_t go = (size_t)(col0 + n) * KP + k0 + (lane & 3) * 8;
            __builtin_amdgcn_global_load_lds((AS1 void*)(Bthi + go),
                                             (AS3 void*)(Bhi + s * 512), 16, 0, 0);
            __builtin_amdgcn_global_load_lds((AS1 void*)(Btlo + go),
                                             (AS3 void*)(Blo + s * 512), 16, 0, 0);
        }
        __syncthreads();   // drains vmcnt+lgkmcnt, then barrier

        // ---- compute: 48 MFMA ----
        short8 ah[4], al[4];
        #pragma unroll
        for (int m = 0; m < 4; ++m) {
            const int r = wr * 64 + m * 16 + (lane & 15);
            const int o = r * 32 + (lane >> 4) * 8;
            ah[m] = *reinterpret_cast<const short8*>(&Ahi[o]);
            al[m] = *reinterpret_cast<const short8*>(&Alo[o]);
        }
        #pragma unroll
        for (int n = 0; n < 4; ++n) {
            const int r = wc * 64 + n * 16 + (lane & 15);
            const int o = r * 32 + (lane >> 4) * 8;
            const short8 bh = *reinterpret_cast<const short8*>(&Bhi[o]);
            const short8 bl = *reinterpret_cast<const short8*>(&Blo[o]);
            #pragma unroll
            for (int m = 0; m < 4; ++m) {
                acc[m][n] = __builtin_amdgcn_mfma_f32_16x16x32_bf16(ah[m], bh, acc[m][n], 0, 0, 0);
                acc[m][n] = __builtin_amdgcn_mfma_f32_16x16x32_bf16(al[m], bh, acc[m][n], 0, 0, 0);
                acc[m][n] = __builtin_amdgcn_mfma_f32_16x16x32_bf16(ah[m], bl, acc[m][n], 0, 0, 0);
            }
        }
    }

    // ---- epilogue: bias + store ----
    float bv[4];
    #pragma unroll
    for (int n = 0; n < 4; ++n)
        bv[n] = bias[col0 + wc * 64 + n * 16 + (lane & 15)];
    #pragma unroll
    for (int m = 0; m < 4; ++m)
        #pragma unroll
        for (int j = 0; j < 4; ++j) {
            const int gr = row0 + wr * 64 + m * 16 + (lane >> 4) * 4 + j;
            float* dst = C + (size_t)gr * N + col0 + wc * 64 + (lane & 15);
            #pragma unroll
            for (int n = 0; n < 4; ++n)
                dst[n * 16] = acc[m][n][j] + bv[n];
        }
}

// ==================================================================
// FALLBACK PATH (known-good fp32, used if ws_size is too small)
// ==================================================================
__global__ __launch_bounds__(256)
void sgemm_bias(const float* __restrict__ A, const float* __restrict__ Bm,
                const float* __restrict__ bias, float* __restrict__ C,
                int M, int N, int K)
{
    __shared__ float As[16][136];
    __shared__ float Bs[16][136];
    const int tid = threadIdx.x;
    const int tx  = tid & 15;
    const int ty  = tid >> 4;
    const int row0 = blockIdx.y * 128;
    const int col0 = blockIdx.x * 128;
    const int ar = tid >> 2;
    const int ac = (tid & 3) << 2;
    const int br = tid >> 5;
    const int bc = (tid & 31) << 2;
    float acc[8][8];
    #pragma unroll
    for (int i = 0; i < 8; ++i)
        #pragma unroll
        for (int j = 0; j < 8; ++j) acc[i][j] = 0.f;
    for (int k0 = 0; k0 < K; k0 += 16) {
        __syncthreads();
        #pragma unroll
        for (int h = 0; h < 2; ++h) {
            const int r = ar + h * 64;
            const float* src = A + (size_t)(row0 + r) * K + k0 + ac;
            float4 v;
            if (k0 + ac + 4 <= K) {
                v = *reinterpret_cast<const float4*>(src);
            } else {
                v.x = (k0 + ac + 0 < K) ? src[0] : 0.f;
                v.y = (k0 + ac + 1 < K) ? src[1] : 0.f;
                v.z = (k0 + ac + 2 < K) ? src[2] : 0.f;
                v.w = (k0 + ac + 3 < K) ? src[3] : 0.f;
            }
            As[ac + 0][r] = v.x; As[ac + 1][r] = v.y;
            As[ac + 2][r] = v.z; As[ac + 3][r] = v.w;
        }
        #pragma unroll
        for (int h = 0; h < 2; ++h) {
            const int r = br + h * 8;
            float4 v = make_float4(0.f, 0.f, 0.f, 0.f);
            if (k0 + r < K)
                v = *reinterpret_cast<const float4*>(Bm + (size_t)(k0 + r) * N + col0 + bc);
            *reinterpret_cast<float4*>(&Bs[r][bc]) = v;
        }
        __syncthreads();
        #pragma unroll
        for (int kk = 0; kk < 16; ++kk) {
            float a[8], b[8];
            *reinterpret_cast<float4*>(&a[0]) = *reinterpret_cast<const float4*>(&As[kk][ty * 8]);
            *reinterpret_cast<float4*>(&a[4]) = *reinterpret_cast<const float4*>(&As[kk][ty * 8 + 4]);
            *reinterpret_cast<float4*>(&b[0]) = *reinterpret_cast<const float4*>(&Bs[kk][tx * 8]);
            *reinterpret_cast<float4*>(&b[4]) = *reinterpret_cast<const float4*>(&Bs[kk][tx * 8 + 4]);
            #pragma unroll
            for (int i = 0; i < 8; ++i)
                #pragma unroll
                for (int j = 0; j < 8; ++j)
                    acc[i][j] = fmaf(a[i], b[j], acc[i][j]);
        }
    }
    float bvv[8];
    *reinterpret_cast<float4*>(&bvv[0]) = *reinterpret_cast<const float4*>(bias + col0 + tx * 8);
    *reinterpret_cast<float4*>(&bvv[4]) = *reinterpret_cast<const float4*>(bias + col0 + tx * 8 + 4);
    #pragma unroll
    for (int i = 0; i < 8; ++i) {
        float* dst = C + (size_t)(row0 + ty * 8 + i) * N + col0 + tx * 8;
        float4 o0 = make_float4(acc[i][0] + bvv[0], acc[i][1] + bvv[1],
                                acc[i][2] + bvv[2], acc[i][3] + bvv[3]);
        float4 o1 = make_float4(acc[i][4] + bvv[4], acc[i][5] + bvv[5],
                                acc[i][6] + bvv[6], acc[i][7] + bvv[7]);
        *reinterpret_cast<float4*>(dst)     = o0;
        *reinterpret_cast<float4*>(dst + 4) = o1;
    }
}

// ==================================================================
// Shared downstream kernels (unchanged, known-pass)
// ==================================================================
__global__ __launch_bounds__(256)
void l2norm_rows(float* __restrict__ X)
{
    __shared__ float red[4];
    const int tid = threadIdx.x;
    float4* p = reinterpret_cast<float4*>(X + (size_t)blockIdx.x * DEMB);
    float4 v = p[tid];
    float ss = v.x * v.x + v.y * v.y + v.z * v.z + v.w * v.w;
    #pragma unroll
    for (int o = 32; o; o >>= 1) ss += __shfl_xor(ss, o);
    if ((tid & 63) == 0) red[tid >> 6] = ss;
    __syncthreads();
    const float sc = rsqrtf(red[0] + red[1] + red[2] + red[3] + 1e-12f);
    v.x *= sc; v.y *= sc; v.z *= sc; v.w *= sc;
    p[tid] = v;
}

__device__ __forceinline__ float wred(float v)
{
    #pragma unroll
    for (int o = 32; o; o >>= 1) v += __shfl_xor(v, o);
    return v;
}

__global__ __launch_bounds__(256)
void scan_attention(const float* __restrict__ img, const float* __restrict__ cap,
                    const int* __restrict__ lens, float* __restrict__ out)
{
    __shared__ float simg[12 * 1024];
    __shared__ float swt[NL][NR + 1];
    __shared__ float accv[3][NL];
    __shared__ float wsum[4];

    const int b    = blockIdx.x;
    const int tid  = threadIdx.x;
    const int w    = tid >> 6;
    const int lane = tid & 63;
    const int len  = lens[b];
    const float* imgb = img + (size_t)b * NR * DEMB;
    const float* capb = cap + (size_t)b * NL * DEMB;

    for (int rc = 0; rc < 3; ++rc) {
        __syncthreads();
        {
            const float4* src = reinterpret_cast<const float4*>(imgb + (size_t)rc * 12 * DEMB);
            float4* dst = reinterpret_cast<float4*>(simg);
            #pragma unroll
            for (int t = 0; t < 12; ++t) dst[tid + t * 256] = src[tid + t * 256];
        }
        __syncthreads();
        for (int i = 0; i < 15; ++i) {
            const int l = w + i * 4;
            float c[16];
            #pragma unroll
            for (int j = 0; j < 16; ++j) c[j] = capb[(size_t)l * DEMB + j * 64 + lane];
            if (rc == 0) {
                float s2 = 0.f;
                #pragma unroll
                for (int j = 0; j < 16; ++j) s2 = fmaf(c[j], c[j], s2);
                s2 = wred(s2);
                if (lane == 0) accv[0][l] = s2;
            }
            for (int r = 0; r < 12; ++r) {
                float p = 0.f;
                #pragma unroll
                for (int j = 0; j < 16; ++j)
                    p = fmaf(c[j], simg[r * 1024 + j * 64 + lane], p);
                p = wred(p);
                if (lane == 0) swt[l][rc * 12 + r] = p;
            }
        }
    }

    for (int i = 0; i < 15; ++i) {
        const int l = w + i * 4;
        float m = -1e30f;
        for (int r = 0; r < NR; ++r) m = fmaxf(m, swt[l][r]);
        float e = 0.f;
        if (lane < NR) e = __expf(9.f * (swt[l][lane] - m));
        if (lane < NR) swt[l][lane] = e;
    }

    for (int dc = 0; dc < 4; ++dc) {
        __syncthreads();
        {
            float4* dst = reinterpret_cast<float4*>(simg);
            #pragma unroll
            for (int t = 0; t < 9; ++t) {
                const int f  = tid + t * 256;
                const int r  = f >> 6;
                const int c4 = f & 63;
                dst[f] = *reinterpret_cast<const float4*>(
                    imgb + (size_t)r * DEMB + dc * 256 + c4 * 4);
            }
        }
        __syncthreads();
        for (int i = 0; i < 15; ++i) {
            const int l = w + i * 4;
            float cj[4];
            #pragma unroll
            for (int j = 0; j < 4; ++j)
                cj[j] = capb[(size_t)l * DEMB + dc * 256 + j * 64 + lane];
            float np = 0.f, ap = 0.f;
            #pragma unroll
            for (int j = 0; j < 4; ++j) {
                float a = 0.f;
                #pragma unroll
                for (int r = 0; r < NR; ++r)
                    a = fmaf(swt[l][r], simg[r * 256 + j * 64 + lane], a);
                np = fmaf(cj[j], a, np);
                ap = fmaf(a, a, ap);
            }
            np = wred(np);
            ap = wred(ap);
            if (lane == 0) {
                if (dc == 0) { accv[1][l] = np;  accv[2][l] = ap; }
                else         { accv[1][l] += np; accv[2][l] += ap; }
            }
        }
    }

    if (lane == 0) {
        float wacc = 0.f;
        for (int i = 0; i < 15; ++i) {
            const int l = w + i * 4;
            if (l < len) {
                const float ncap = fmaxf(sqrtf(accv[0][l]), 1e-8f);
                const float natt = fmaxf(sqrtf(accv[2][l]), 1e-8f);
                wacc += accv[1][l] / (ncap * natt);
            }
        }
        wsum[w] = wacc;
    }
    __syncthreads();
    if (tid == 0)
        out[b] = (wsum[0] + wsum[1] + wsum[2] + wsum[3]) / (float)len;
}

// ==================================================================
extern "C" void kernel_launch(void* const* d_in, const int* in_sizes, int n_in,
                              void* d_out, int out_size, void* d_ws, size_t ws_size,
                              hipStream_t stream)
{
    const float* images   = (const float*)d_in[0];
    const float* captions = (const float*)d_in[1];
    const int*   lens     = (const int*)  d_in[2];
    const float* W_img    = (const float*)d_in[3];
    const float* b_img    = (const float*)d_in[4];
    const float* W_txt    = (const float*)d_in[5];
    const float* b_txt    = (const float*)d_in[6];
    float*       out      = (float*)d_out;

    const size_t EMB_BYTES   = (size_t)(NB * NR + NB * NL) * DEMB * 4;       // 100,663,296
    const size_t WIMG_T      = (size_t)DEMB * DIMG * 2;                      // 4 MiB per half
    const size_t WTXT_T      = (size_t)DEMB * 320 * 2;
    const size_t NEED_FAST   = EMB_BYTES + 2 * WIMG_T + 2 * WTXT_T;          // ~110.4 MB

    char* base = (char*)d_ws;
    float* img_embs = (float*)base;                                          // 9216 x 1024
    float* cap_embs = (float*)(base + (size_t)NB * NR * DEMB * 4);           // 15360 x 1024

    if (ws_size >= NEED_FAST) {
        short* WimgT_hi = (short*)(base + EMB_BYTES);
        short* WimgT_lo = (short*)(base + EMB_BYTES + WIMG_T);
        short* WtxtT_hi = (short*)(base + EMB_BYTES + 2 * WIMG_T);
        short* WtxtT_lo = (short*)(base + EMB_BYTES + 2 * WIMG_T + WTXT_T);

        split_transpose<<<dim3(DIMG / 64, DEMB / 64), 256, 0, stream>>>(
            W_img, WimgT_hi, WimgT_lo, DIMG, DEMB, DIMG);
        split_transpose<<<dim3(320 / 64, DEMB / 64), 256, 0, stream>>>(
            W_txt, WtxtT_hi, WtxtT_lo, DWRD, DEMB, 320);

        gemm_asplit<<<dim3(DEMB / 128, (NB * NR) / 128), 256, 0, stream>>>(
            images, WimgT_hi, WimgT_lo, b_img, img_embs, NB * NR, DEMB, DIMG, DIMG);
        gemm_asplit<<<dim3(DEMB / 128, (NB * NL) / 128), 256, 0, stream>>>(
            captions, WtxtT_hi, WtxtT_lo, b_txt, cap_embs, NB * NL, DEMB, DWRD, 320);
    } else {
        sgemm_bias<<<dim3(DEMB / 128, (NB * NR) / 128), 256, 0, stream>>>(
            images, W_img, b_img, img_embs, NB * NR, DEMB, DIMG);
        sgemm_bias<<<dim3(DEMB / 128, (NB * NL) / 128), 256, 0, stream>>>(
            captions, W_txt, b_txt, cap_embs, NB * NL, DEMB, DWRD);
    }

    l2norm_rows<<<NB * NR, 256, 0, stream>>>(img_embs);
    l2norm_rows<<<NB * NL, 256, 0, stream>>>(cap_embs);

    scan_attention<<<NB, 256, 0, stream>>>(img_embs, cap_embs, lens, out);
}

// Round 4
// 614.591 us; speedup vs baseline: 1.8276x; 1.0706x over previous
//
#include <hip/hip_runtime.h>
#include <math.h>

// Shapes (fixed by the problem)
#define NB   256
#define NR   36
#define NL   60
#define DIMG 2048
#define DWRD 300
#define DEMB 1024

typedef __attribute__((ext_vector_type(8))) short short8;
typedef __attribute__((ext_vector_type(4))) short short4v;
typedef __attribute__((ext_vector_type(4))) float f32x4;

#define AS1 __attribute__((address_space(1)))
#define AS3 __attribute__((address_space(3)))

__device__ __forceinline__ unsigned short bf16_rne(float x) {
    unsigned u = __builtin_bit_cast(unsigned, x);
    unsigned r = u + 0x7FFFu + ((u >> 16) & 1u);
    return (unsigned short)(r >> 16);
}
__device__ __forceinline__ float bf16_to_f(unsigned short h) {
    unsigned u = ((unsigned)h) << 16;
    return __builtin_bit_cast(float, u);
}

__device__ __forceinline__ float wred(float v)
{
    #pragma unroll
    for (int o = 32; o; o >>= 1) v += __shfl_xor(v, o);
    return v;
}

// ==================================================================
// Encoder GEMM fast path (bf16 split-precision MFMA) — unchanged
// ==================================================================
__global__ __launch_bounds__(256)
void split_transpose(const float* __restrict__ W, short* __restrict__ Thi,
                     short* __restrict__ Tlo, int K, int N, int KP)
{
    __shared__ float T[64][68];
    const int t = threadIdx.x;
    const int k0 = blockIdx.x * 64, n0 = blockIdx.y * 64;
    #pragma unroll
    for (int q = 0; q < 4; ++q) {
        const int r = (t >> 4) + q * 16;
        const int c4 = (t & 15) * 4;
        float4 v = make_float4(0.f, 0.f, 0.f, 0.f);
        if (k0 + r < K)
            v = *reinterpret_cast<const float4*>(W + (size_t)(k0 + r) * N + n0 + c4);
        T[r][c4] = v.x; T[r][c4 + 1] = v.y; T[r][c4 + 2] = v.z; T[r][c4 + 3] = v.w;
    }
    __syncthreads();
    #pragma unroll
    for (int q = 0; q < 4; ++q) {
        const int nl = (t >> 4) + q * 16;
        const int kc = (t & 15) * 4;
        short hs[4] __attribute__((aligned(8)));
        short ls[4] __attribute__((aligned(8)));
        #pragma unroll
        for (int i = 0; i < 4; ++i) {
            const float x = T[kc + i][nl];
            const unsigned short hb = bf16_rne(x);
            hs[i] = (short)hb;
            ls[i] = (short)bf16_rne(x - bf16_to_f(hb));
        }
        const size_t o = (size_t)(n0 + nl) * KP + k0 + kc;
        *reinterpret_cast<short4v*>(Thi + o) = *reinterpret_cast<short4v*>(hs);
        *reinterpret_cast<short4v*>(Tlo + o) = *reinterpret_cast<short4v*>(ls);
    }
}

__global__ __launch_bounds__(256)
void gemm_asplit(const float* __restrict__ A, const short* __restrict__ Bthi,
                 const short* __restrict__ Btlo, const float* __restrict__ bias,
                 float* __restrict__ C, int M, int N, int K, int KP)
{
    __shared__ short Ahi[128 * 32], Alo[128 * 32];
    __shared__ short Bhi[128 * 32], Blo[128 * 32];

    const int tid  = threadIdx.x;
    const int w    = tid >> 6, lane = tid & 63;
    const int wr   = w >> 1,   wc   = w & 1;
    const int row0 = blockIdx.y * 128, col0 = blockIdx.x * 128;

    f32x4 acc[4][4];
    #pragma unroll
    for (int m = 0; m < 4; ++m)
        #pragma unroll
        for (int n = 0; n < 4; ++n)
            acc[m][n] = (f32x4){0.f, 0.f, 0.f, 0.f};

    for (int k0 = 0; k0 < KP; k0 += 32) {
        __syncthreads();
        #pragma unroll
        for (int h = 0; h < 2; ++h) {
            const int c = tid + h * 256;
            const int r = c >> 2;
            const int ke = (c & 3) * 8;
            const int gk = k0 + ke;
            const float* src = A + (size_t)(row0 + r) * K + gk;
            float v[8] __attribute__((aligned(16)));
            if (gk + 8 <= K) {
                *reinterpret_cast<float4*>(&v[0]) = *reinterpret_cast<const float4*>(src);
                *reinterpret_cast<float4*>(&v[4]) = *reinterpret_cast<const float4*>(src + 4);
            } else {
                #pragma unroll
                for (int i = 0; i < 8; ++i)
                    v[i] = (gk + i < K) ? src[i] : 0.f;
            }
            short hs[8] __attribute__((aligned(16)));
            short ls[8] __attribute__((aligned(16)));
            #pragma unroll
            for (int i = 0; i < 8; ++i) {
                const unsigned short hb = bf16_rne(v[i]);
                hs[i] = (short)hb;
                ls[i] = (short)bf16_rne(v[i] - bf16_to_f(hb));
            }
            *reinterpret_cast<short8*>(&Ahi[c * 8]) = *reinterpret_cast<short8*>(hs);
            *reinterpret_cast<short8*>(&Alo[c * 8]) = *reinterpret_cast<short8*>(ls);
        }
        #pragma unroll
        for (int j = 0; j < 2; ++j) {
            const int s = w * 2 + j;
            const int n = 16 * s + (lane >> 2);
            const size_t go = (size_t)(col0 + n) * KP + k0 + (lane & 3) * 8;
            __builtin_amdgcn_global_load_lds((AS1 void*)(Bthi + go),
                                             (AS3 void*)(Bhi + s * 512), 16, 0, 0);
            __builtin_amdgcn_global_load_lds((AS1 void*)(Btlo + go),
                                             (AS3 void*)(Blo + s * 512), 16, 0, 0);
        }
        __syncthreads();

        short8 ah[4], al[4];
        #pragma unroll
        for (int m = 0; m < 4; ++m) {
            const int r = wr * 64 + m * 16 + (lane & 15);
            const int o = r * 32 + (lane >> 4) * 8;
            ah[m] = *reinterpret_cast<const short8*>(&Ahi[o]);
            al[m] = *reinterpret_cast<const short8*>(&Alo[o]);
        }
        #pragma unroll
        for (int n = 0; n < 4; ++n) {
            const int r = wc * 64 + n * 16 + (lane & 15);
            const int o = r * 32 + (lane >> 4) * 8;
            const short8 bh = *reinterpret_cast<const short8*>(&Bhi[o]);
            const short8 bl = *reinterpret_cast<const short8*>(&Blo[o]);
            #pragma unroll
            for (int m = 0; m < 4; ++m) {
                acc[m][n] = __builtin_amdgcn_mfma_f32_16x16x32_bf16(ah[m], bh, acc[m][n], 0, 0, 0);
                acc[m][n] = __builtin_amdgcn_mfma_f32_16x16x32_bf16(al[m], bh, acc[m][n], 0, 0, 0);
                acc[m][n] = __builtin_amdgcn_mfma_f32_16x16x32_bf16(ah[m], bl, acc[m][n], 0, 0, 0);
            }
        }
    }

    float bv[4];
    #pragma unroll
    for (int n = 0; n < 4; ++n)
        bv[n] = bias[col0 + wc * 64 + n * 16 + (lane & 15)];
    #pragma unroll
    for (int m = 0; m < 4; ++m)
        #pragma unroll
        for (int j = 0; j < 4; ++j) {
            const int gr = row0 + wr * 64 + m * 16 + (lane >> 4) * 4 + j;
            float* dst = C + (size_t)gr * N + col0 + wc * 64 + (lane & 15);
            #pragma unroll
            for (int n = 0; n < 4; ++n)
                dst[n * 16] = acc[m][n][j] + bv[n];
        }
}

// ==================================================================
// Fallback fp32 GEMM (ws too small) — unchanged
// ==================================================================
__global__ __launch_bounds__(256)
void sgemm_bias(const float* __restrict__ A, const float* __restrict__ Bm,
                const float* __restrict__ bias, float* __restrict__ C,
                int M, int N, int K)
{
    __shared__ float As[16][136];
    __shared__ float Bs[16][136];
    const int tid = threadIdx.x;
    const int tx  = tid & 15;
    const int ty  = tid >> 4;
    const int row0 = blockIdx.y * 128;
    const int col0 = blockIdx.x * 128;
    const int ar = tid >> 2;
    const int ac = (tid & 3) << 2;
    const int br = tid >> 5;
    const int bc = (tid & 31) << 2;
    float acc[8][8];
    #pragma unroll
    for (int i = 0; i < 8; ++i)
        #pragma unroll
        for (int j = 0; j < 8; ++j) acc[i][j] = 0.f;
    for (int k0 = 0; k0 < K; k0 += 16) {
        __syncthreads();
        #pragma unroll
        for (int h = 0; h < 2; ++h) {
            const int r = ar + h * 64;
            const float* src = A + (size_t)(row0 + r) * K + k0 + ac;
            float4 v;
            if (k0 + ac + 4 <= K) {
                v = *reinterpret_cast<const float4*>(src);
            } else {
                v.x = (k0 + ac + 0 < K) ? src[0] : 0.f;
                v.y = (k0 + ac + 1 < K) ? src[1] : 0.f;
                v.z = (k0 + ac + 2 < K) ? src[2] : 0.f;
                v.w = (k0 + ac + 3 < K) ? src[3] : 0.f;
            }
            As[ac + 0][r] = v.x; As[ac + 1][r] = v.y;
            As[ac + 2][r] = v.z; As[ac + 3][r] = v.w;
        }
        #pragma unroll
        for (int h = 0; h < 2; ++h) {
            const int r = br + h * 8;
            float4 v = make_float4(0.f, 0.f, 0.f, 0.f);
            if (k0 + r < K)
                v = *reinterpret_cast<const float4*>(Bm + (size_t)(k0 + r) * N + col0 + bc);
            *reinterpret_cast<float4*>(&Bs[r][bc]) = v;
        }
        __syncthreads();
        #pragma unroll
        for (int kk = 0; kk < 16; ++kk) {
            float a[8], b[8];
            *reinterpret_cast<float4*>(&a[0]) = *reinterpret_cast<const float4*>(&As[kk][ty * 8]);
            *reinterpret_cast<float4*>(&a[4]) = *reinterpret_cast<const float4*>(&As[kk][ty * 8 + 4]);
            *reinterpret_cast<float4*>(&b[0]) = *reinterpret_cast<const float4*>(&Bs[kk][tx * 8]);
            *reinterpret_cast<float4*>(&b[4]) = *reinterpret_cast<const float4*>(&Bs[kk][tx * 8 + 4]);
            #pragma unroll
            for (int i = 0; i < 8; ++i)
                #pragma unroll
                for (int j = 0; j < 8; ++j)
                    acc[i][j] = fmaf(a[i], b[j], acc[i][j]);
        }
    }
    float bvv[8];
    *reinterpret_cast<float4*>(&bvv[0]) = *reinterpret_cast<const float4*>(bias + col0 + tx * 8);
    *reinterpret_cast<float4*>(&bvv[4]) = *reinterpret_cast<const float4*>(bias + col0 + tx * 8 + 4);
    #pragma unroll
    for (int i = 0; i < 8; ++i) {
        float* dst = C + (size_t)(row0 + ty * 8 + i) * N + col0 + tx * 8;
        float4 o0 = make_float4(acc[i][0] + bvv[0], acc[i][1] + bvv[1],
                                acc[i][2] + bvv[2], acc[i][3] + bvv[3]);
        float4 o1 = make_float4(acc[i][4] + bvv[4], acc[i][5] + bvv[5],
                                acc[i][6] + bvv[6], acc[i][7] + bvv[7]);
        *reinterpret_cast<float4*>(dst)     = o0;
        *reinterpret_cast<float4*>(dst + 4) = o1;
    }
}

// ==================================================================
// L2 normalization — unchanged
// ==================================================================
__global__ __launch_bounds__(256)
void l2norm_rows(float* __restrict__ X)
{
    __shared__ float red[4];
    const int tid = threadIdx.x;
    float4* p = reinterpret_cast<float4*>(X + (size_t)blockIdx.x * DEMB);
    float4 v = p[tid];
    float ss = v.x * v.x + v.y * v.y + v.z * v.z + v.w * v.w;
    #pragma unroll
    for (int o = 32; o; o >>= 1) ss += __shfl_xor(ss, o);
    if ((tid & 63) == 0) red[tid >> 6] = ss;
    __syncthreads();
    const float sc = rsqrtf(red[0] + red[1] + red[2] + red[3] + 1e-12f);
    v.x *= sc; v.y *= sc; v.z *= sc; v.w *= sc;
    p[tid] = v;
}

// ==================================================================
// NEW: per-batch Gram matrix G = img @ img^T (36x36), img rows unit-norm.
// One block per batch, 4 waves; wave w owns rows r = w, w+4, ...
// ==================================================================
__global__ __launch_bounds__(256)
void gram_kernel(const float* __restrict__ img, float* __restrict__ G)
{
    const int b = blockIdx.x;
    const int w = threadIdx.x >> 6, lane = threadIdx.x & 63;
    const float* X = img + (size_t)b * NR * DEMB;
    float* Gb = G + (size_t)b * NR * NR;
    for (int r = w; r < NR; r += 4) {
        float c[16];
        #pragma unroll
        for (int j = 0; j < 16; ++j) c[j] = X[(size_t)r * DEMB + j * 64 + lane];
        for (int rp = r; rp < NR; ++rp) {
            float p = 0.f;
            #pragma unroll
            for (int j = 0; j < 16; ++j)
                p = fmaf(c[j], X[(size_t)rp * DEMB + j * 64 + lane], p);
            p = wred(p);
            if (lane == 0) { Gb[r * NR + rp] = p; Gb[rp * NR + r] = p; }
        }
    }
}

// ==================================================================
// NEW: attention via S + Gram. Grid (4 word-groups, 256 batches).
// Each block: 15 words. Phase 1: S[15][36] over 6-row img chunks.
// Finalize: w = exp(9(s-m)); num = w.s ; ||att||^2 = w^T G w ; atomicAdd.
// ==================================================================
#define CH 6
__global__ __launch_bounds__(256)
void scan_attn2(const float* __restrict__ img, const float* __restrict__ cap,
                const float* __restrict__ G, const int* __restrict__ lens,
                float* __restrict__ out)
{
    __shared__ float simg[CH * 1024];    // 24KB
    __shared__ float sS[15][37];
    __shared__ float sE[15][37];
    __shared__ float sG[36][37];         // 5.3KB
    __shared__ float scap[15];
    __shared__ float wsum[4];

    const int g = blockIdx.x;            // word group 0..3
    const int b = blockIdx.y;
    const int tid = threadIdx.x, w = tid >> 6, lane = tid & 63;
    const int len = lens[b];
    const int l0 = g * 15;
    const float* imgb = img + (size_t)b * NR * DEMB;
    const float* capb = cap + (size_t)b * NL * DEMB;

    // stage G (covered by first chunk's __syncthreads)
    for (int t = tid; t < NR * NR; t += 256)
        sG[t / 36][t % 36] = G[(size_t)b * (NR * NR) + t];

    // ---- Phase 1: similarity scores over 6 chunks of 6 img rows ----
    for (int rc = 0; rc < 6; ++rc) {
        __syncthreads();
        {
            const float4* src = reinterpret_cast<const float4*>(imgb + (size_t)rc * CH * DEMB);
            float4* dst = reinterpret_cast<float4*>(simg);
            #pragma unroll
            for (int t = 0; t < 6; ++t) dst[tid + t * 256] = src[tid + t * 256];
        }
        __syncthreads();
        for (int i = w; i < 15; i += 4) {
            const int l = l0 + i;
            float c[16];
            #pragma unroll
            for (int j = 0; j < 16; ++j) c[j] = capb[(size_t)l * DEMB + j * 64 + lane];
            if (rc == 0) {
                float s2 = 0.f;
                #pragma unroll
                for (int j = 0; j < 16; ++j) s2 = fmaf(c[j], c[j], s2);
                s2 = wred(s2);
                if (lane == 0) scap[i] = s2;
            }
            #pragma unroll
            for (int r = 0; r < CH; ++r) {
                float p = 0.f;
                #pragma unroll
                for (int j = 0; j < 16; ++j)
                    p = fmaf(c[j], simg[r * 1024 + j * 64 + lane], p);
                p = wred(p);
                if (lane == 0) sS[i][rc * CH + r] = p;
            }
        }
    }

    // ---- Finalize per word (wave-local; no cross-wave LDS sharing) ----
    float wacc = 0.f;
    for (int i = w; i < 15; i += 4) {
        const int l = l0 + i;
        const float sv = (lane < NR) ? sS[i][lane] : -1e30f;
        float m = sv;
        #pragma unroll
        for (int o = 32; o; o >>= 1) m = fmaxf(m, __shfl_xor(m, o));
        const float e = (lane < NR) ? __expf(9.f * (sv - m)) : 0.f;
        if (lane < NR) sE[i][lane] = e;
        float num = 0.f, aq = 0.f;
        if (lane < NR) {
            float q = 0.f;
            #pragma unroll
            for (int rp = 0; rp < NR; ++rp)
                q = fmaf(sG[lane][rp], sE[i][rp], q);
            num = e * sv;
            aq  = e * q;
        }
        num = wred(num);
        aq  = wred(aq);
        if (lane == 0 && l < len) {
            const float ncap = fmaxf(sqrtf(scap[i]), 1e-8f);
            const float natt = fmaxf(sqrtf(aq), 1e-8f);
            wacc += num / (ncap * natt);
        }
    }
    if (lane == 0) wsum[w] = wacc;
    __syncthreads();
    if (tid == 0) {
        const float s = wsum[0] + wsum[1] + wsum[2] + wsum[3];
        atomicAdd(out + b, s / (float)len);
    }
}

// ==================================================================
extern "C" void kernel_launch(void* const* d_in, const int* in_sizes, int n_in,
                              void* d_out, int out_size, void* d_ws, size_t ws_size,
                              hipStream_t stream)
{
    const float* images   = (const float*)d_in[0];
    const float* captions = (const float*)d_in[1];
    const int*   lens     = (const int*)  d_in[2];
    const float* W_img    = (const float*)d_in[3];
    const float* b_img    = (const float*)d_in[4];
    const float* W_txt    = (const float*)d_in[5];
    const float* b_txt    = (const float*)d_in[6];
    float*       out      = (float*)d_out;

    const size_t EMB_BYTES = (size_t)(NB * NR + NB * NL) * DEMB * 4;
    const size_t WIMG_T    = (size_t)DEMB * DIMG * 2;
    const size_t WTXT_T    = (size_t)DEMB * 320 * 2;
    const size_t NEED_FAST = EMB_BYTES + 2 * WIMG_T + 2 * WTXT_T;

    char* base = (char*)d_ws;
    float* img_embs = (float*)base;
    float* cap_embs = (float*)(base + (size_t)NB * NR * DEMB * 4);
    // G overlays the W-split region (consumed before gram_kernel runs).
    float* Gm = (float*)(base + EMB_BYTES);

    if (ws_size >= NEED_FAST) {
        short* WimgT_hi = (short*)(base + EMB_BYTES);
        short* WimgT_lo = (short*)(base + EMB_BYTES + WIMG_T);
        short* WtxtT_hi = (short*)(base + EMB_BYTES + 2 * WIMG_T);
        short* WtxtT_lo = (short*)(base + EMB_BYTES + 2 * WIMG_T + WTXT_T);

        split_transpose<<<dim3(DIMG / 64, DEMB / 64), 256, 0, stream>>>(
            W_img, WimgT_hi, WimgT_lo, DIMG, DEMB, DIMG);
        split_transpose<<<dim3(320 / 64, DEMB / 64), 256, 0, stream>>>(
            W_txt, WtxtT_hi, WtxtT_lo, DWRD, DEMB, 320);

        gemm_asplit<<<dim3(DEMB / 128, (NB * NR) / 128), 256, 0, stream>>>(
            images, WimgT_hi, WimgT_lo, b_img, img_embs, NB * NR, DEMB, DIMG, DIMG);
        gemm_asplit<<<dim3(DEMB / 128, (NB * NL) / 128), 256, 0, stream>>>(
            captions, WtxtT_hi, WtxtT_lo, b_txt, cap_embs, NB * NL, DEMB, DWRD, 320);
    } else {
        sgemm_bias<<<dim3(DEMB / 128, (NB * NR) / 128), 256, 0, stream>>>(
            images, W_img, b_img, img_embs, NB * NR, DEMB, DIMG);
        sgemm_bias<<<dim3(DEMB / 128, (NB * NL) / 128), 256, 0, stream>>>(
            captions, W_txt, b_txt, cap_embs, NB * NL, DEMB, DWRD);
    }

    l2norm_rows<<<NB * NR, 256, 0, stream>>>(img_embs);
    l2norm_rows<<<NB * NL, 256, 0, stream>>>(cap_embs);

    // Gram matrices (after img l2norm; overwrites spent W-split region)
    gram_kernel<<<NB, 256, 0, stream>>>(img_embs, Gm);

    hipMemsetAsync(d_out, 0, NB * sizeof(float), stream);
    scan_attn2<<<dim3(4, NB), 256, 0, stream>>>(img_embs, cap_embs, Gm, lens, out);
}

// Round 5
// 594.085 us; speedup vs baseline: 1.8907x; 1.0345x over previous
//
#include <hip/hip_runtime.h>
#include <math.h>

// Shapes (fixed by the problem)
#define NB   256
#define NR   36
#define NL   60
#define DIMG 2048
#define DWRD 300
#define DEMB 1024
#define KPC  320   // captions K padded

typedef __attribute__((ext_vector_type(8))) short short8;
typedef __attribute__((ext_vector_type(4))) short short4v;
typedef __attribute__((ext_vector_type(4))) float f32x4;

#define AS1 __attribute__((address_space(1)))
#define AS3 __attribute__((address_space(3)))

__device__ __forceinline__ unsigned short bf16_rne(float x) {
    unsigned u = __builtin_bit_cast(unsigned, x);
    unsigned r = u + 0x7FFFu + ((u >> 16) & 1u);
    return (unsigned short)(r >> 16);
}
__device__ __forceinline__ float bf16_to_f(unsigned short h) {
    unsigned u = ((unsigned)h) << 16;
    return __builtin_bit_cast(float, u);
}

__device__ __forceinline__ float wred(float v)
{
    #pragma unroll
    for (int o = 32; o; o >>= 1) v += __shfl_xor(v, o);
    return v;
}

// ==================================================================
// W (K x N f32) -> Wt_hi/Wt_lo (N x KP bf16), zero-padded. Unchanged.
// ==================================================================
__global__ __launch_bounds__(256)
void split_transpose(const float* __restrict__ W, short* __restrict__ Thi,
                     short* __restrict__ Tlo, int K, int N, int KP)
{
    __shared__ float T[64][68];
    const int t = threadIdx.x;
    const int k0 = blockIdx.x * 64, n0 = blockIdx.y * 64;
    #pragma unroll
    for (int q = 0; q < 4; ++q) {
        const int r = (t >> 4) + q * 16;
        const int c4 = (t & 15) * 4;
        float4 v = make_float4(0.f, 0.f, 0.f, 0.f);
        if (k0 + r < K)
            v = *reinterpret_cast<const float4*>(W + (size_t)(k0 + r) * N + n0 + c4);
        T[r][c4] = v.x; T[r][c4 + 1] = v.y; T[r][c4 + 2] = v.z; T[r][c4 + 3] = v.w;
    }
    __syncthreads();
    #pragma unroll
    for (int q = 0; q < 4; ++q) {
        const int nl = (t >> 4) + q * 16;
        const int kc = (t & 15) * 4;
        short hs[4] __attribute__((aligned(8)));
        short ls[4] __attribute__((aligned(8)));
        #pragma unroll
        for (int i = 0; i < 4; ++i) {
            const float x = T[kc + i][nl];
            const unsigned short hb = bf16_rne(x);
            hs[i] = (short)hb;
            ls[i] = (short)bf16_rne(x - bf16_to_f(hb));
        }
        const size_t o = (size_t)(n0 + nl) * KP + k0 + kc;
        *reinterpret_cast<short4v*>(Thi + o) = *reinterpret_cast<short4v*>(hs);
        *reinterpret_cast<short4v*>(Tlo + o) = *reinterpret_cast<short4v*>(ls);
    }
}

// ==================================================================
// NEW: row-major A (M x K f32) -> A_hi/A_lo (M x KP bf16), zero-padded.
// One 8-elem group per thread; pure streaming.
// ==================================================================
__global__ __launch_bounds__(256)
void split_rows(const float* __restrict__ A, short* __restrict__ Hi,
                short* __restrict__ Lo, int M, int K, int KP)
{
    const int gp  = KP >> 3;
    const int idx = blockIdx.x * 256 + threadIdx.x;
    if (idx >= M * gp) return;
    const int row = idx / gp;
    const int g8  = (idx - row * gp) * 8;

    float v[8] __attribute__((aligned(16)));
    const float* src = A + (size_t)row * K + g8;
    if (g8 + 8 <= K) {
        *reinterpret_cast<float4*>(&v[0]) = *reinterpret_cast<const float4*>(src);
        *reinterpret_cast<float4*>(&v[4]) = *reinterpret_cast<const float4*>(src + 4);
    } else {
        #pragma unroll
        for (int i = 0; i < 8; ++i) v[i] = (g8 + i < K) ? src[i] : 0.f;
    }
    short hs[8] __attribute__((aligned(16)));
    short ls[8] __attribute__((aligned(16)));
    #pragma unroll
    for (int i = 0; i < 8; ++i) {
        const unsigned short hb = bf16_rne(v[i]);
        hs[i] = (short)hb;
        ls[i] = (short)bf16_rne(v[i] - bf16_to_f(hb));
    }
    const size_t o = (size_t)row * KP + g8;
    *reinterpret_cast<short8*>(Hi + o) = *reinterpret_cast<short8*>(hs);
    *reinterpret_cast<short8*>(Lo + o) = *reinterpret_cast<short8*>(ls);
}

// ==================================================================
// NEW: lean GEMM, both operands pre-split bf16, staged via global_load_lds.
// A_hi/A_lo: M x KP row-major; Bt_hi/Bt_lo: N x KP row-major (transposed W).
// 128x128 tile, BK=32, 4 waves. acc += Ah*Bh + Al*Bh + Ah*Bl.
// ==================================================================
__global__ __launch_bounds__(256)
void gemm_presplit(const short* __restrict__ Ahg, const short* __restrict__ Alg,
                   const short* __restrict__ Bhg, const short* __restrict__ Blg,
                   const float* __restrict__ bias, float* __restrict__ C,
                   int M, int N, int KP)
{
    __shared__ short Ahi[128 * 32], Alo[128 * 32];
    __shared__ short Bhi[128 * 32], Blo[128 * 32];

    const int tid  = threadIdx.x;
    const int w    = tid >> 6, lane = tid & 63;
    const int wr   = w >> 1,   wc   = w & 1;
    const int row0 = blockIdx.y * 128, col0 = blockIdx.x * 128;

    f32x4 acc[4][4];
    #pragma unroll
    for (int m = 0; m < 4; ++m)
        #pragma unroll
        for (int n = 0; n < 4; ++n)
            acc[m][n] = (f32x4){0.f, 0.f, 0.f, 0.f};

    for (int k0 = 0; k0 < KP; k0 += 32) {
        __syncthreads();
        // stage: 2 slots/wave/region, 16B per lane, linear LDS dest
        #pragma unroll
        for (int j = 0; j < 2; ++j) {
            const int s  = w * 2 + j;                // slot 0..7 (16 rows)
            const int rr = 16 * s + (lane >> 2);
            const int ko = (lane & 3) * 8;
            const size_t ga = (size_t)(row0 + rr) * KP + k0 + ko;
            const size_t gb = (size_t)(col0 + rr) * KP + k0 + ko;
            __builtin_amdgcn_global_load_lds((AS1 void*)(Ahg + ga),
                                             (AS3 void*)(Ahi + s * 512), 16, 0, 0);
            __builtin_amdgcn_global_load_lds((AS1 void*)(Alg + ga),
                                             (AS3 void*)(Alo + s * 512), 16, 0, 0);
            __builtin_amdgcn_global_load_lds((AS1 void*)(Bhg + gb),
                                             (AS3 void*)(Bhi + s * 512), 16, 0, 0);
            __builtin_amdgcn_global_load_lds((AS1 void*)(Blg + gb),
                                             (AS3 void*)(Blo + s * 512), 16, 0, 0);
        }
        __syncthreads();   // compiler drains vmcnt before barrier

        short8 ah[4], al[4];
        #pragma unroll
        for (int m = 0; m < 4; ++m) {
            const int r = wr * 64 + m * 16 + (lane & 15);
            const int o = r * 32 + (lane >> 4) * 8;
            ah[m] = *reinterpret_cast<const short8*>(&Ahi[o]);
            al[m] = *reinterpret_cast<const short8*>(&Alo[o]);
        }
        #pragma unroll
        for (int n = 0; n < 4; ++n) {
            const int r = wc * 64 + n * 16 + (lane & 15);
            const int o = r * 32 + (lane >> 4) * 8;
            const short8 bh = *reinterpret_cast<const short8*>(&Bhi[o]);
            const short8 bl = *reinterpret_cast<const short8*>(&Blo[o]);
            #pragma unroll
            for (int m = 0; m < 4; ++m) {
                acc[m][n] = __builtin_amdgcn_mfma_f32_16x16x32_bf16(ah[m], bh, acc[m][n], 0, 0, 0);
                acc[m][n] = __builtin_amdgcn_mfma_f32_16x16x32_bf16(al[m], bh, acc[m][n], 0, 0, 0);
                acc[m][n] = __builtin_amdgcn_mfma_f32_16x16x32_bf16(ah[m], bl, acc[m][n], 0, 0, 0);
            }
        }
    }

    float bv[4];
    #pragma unroll
    for (int n = 0; n < 4; ++n)
        bv[n] = bias[col0 + wc * 64 + n * 16 + (lane & 15)];
    #pragma unroll
    for (int m = 0; m < 4; ++m)
        #pragma unroll
        for (int j = 0; j < 4; ++j) {
            const int gr = row0 + wr * 64 + m * 16 + (lane >> 4) * 4 + j;
            float* dst = C + (size_t)gr * N + col0 + wc * 64 + (lane & 15);
            #pragma unroll
            for (int n = 0; n < 4; ++n)
                dst[n * 16] = acc[m][n][j] + bv[n];
        }
}

// ==================================================================
// Round-3 GEMM (on-the-fly A split) — fallback when ws is mid-sized
// ==================================================================
__global__ __launch_bounds__(256)
void gemm_asplit(const float* __restrict__ A, const short* __restrict__ Bthi,
                 const short* __restrict__ Btlo, const float* __restrict__ bias,
                 float* __restrict__ C, int M, int N, int K, int KP)
{
    __shared__ short Ahi[128 * 32], Alo[128 * 32];
    __shared__ short Bhi[128 * 32], Blo[128 * 32];

    const int tid  = threadIdx.x;
    const int w    = tid >> 6, lane = tid & 63;
    const int wr   = w >> 1,   wc   = w & 1;
    const int row0 = blockIdx.y * 128, col0 = blockIdx.x * 128;

    f32x4 acc[4][4];
    #pragma unroll
    for (int m = 0; m < 4; ++m)
        #pragma unroll
        for (int n = 0; n < 4; ++n)
            acc[m][n] = (f32x4){0.f, 0.f, 0.f, 0.f};

    for (int k0 = 0; k0 < KP; k0 += 32) {
        __syncthreads();
        #pragma unroll
        for (int h = 0; h < 2; ++h) {
            const int c = tid + h * 256;
            const int r = c >> 2;
            const int ke = (c & 3) * 8;
            const int gk = k0 + ke;
            const float* src = A + (size_t)(row0 + r) * K + gk;
            float v[8] __attribute__((aligned(16)));
            if (gk + 8 <= K) {
                *reinterpret_cast<float4*>(&v[0]) = *reinterpret_cast<const float4*>(src);
                *reinterpret_cast<float4*>(&v[4]) = *reinterpret_cast<const float4*>(src + 4);
            } else {
                #pragma unroll
                for (int i = 0; i < 8; ++i)
                    v[i] = (gk + i < K) ? src[i] : 0.f;
            }
            short hs[8] __attribute__((aligned(16)));
            short ls[8] __attribute__((aligned(16)));
            #pragma unroll
            for (int i = 0; i < 8; ++i) {
                const unsigned short hb = bf16_rne(v[i]);
                hs[i] = (short)hb;
                ls[i] = (short)bf16_rne(v[i] - bf16_to_f(hb));
            }
            *reinterpret_cast<short8*>(&Ahi[c * 8]) = *reinterpret_cast<short8*>(hs);
            *reinterpret_cast<short8*>(&Alo[c * 8]) = *reinterpret_cast<short8*>(ls);
        }
        #pragma unroll
        for (int j = 0; j < 2; ++j) {
            const int s = w * 2 + j;
            const int n = 16 * s + (lane >> 2);
            const size_t go = (size_t)(col0 + n) * KP + k0 + (lane & 3) * 8;
            __builtin_amdgcn_global_load_lds((AS1 void*)(Bthi + go),
                                             (AS3 void*)(Bhi + s * 512), 16, 0, 0);
            __builtin_amdgcn_global_load_lds((AS1 void*)(Btlo + go),
                                             (AS3 void*)(Blo + s * 512), 16, 0, 0);
        }
        __syncthreads();

        short8 ah[4], al[4];
        #pragma unroll
        for (int m = 0; m < 4; ++m) {
            const int r = wr * 64 + m * 16 + (lane & 15);
            const int o = r * 32 + (lane >> 4) * 8;
            ah[m] = *reinterpret_cast<const short8*>(&Ahi[o]);
            al[m] = *reinterpret_cast<const short8*>(&Alo[o]);
        }
        #pragma unroll
        for (int n = 0; n < 4; ++n) {
            const int r = wc * 64 + n * 16 + (lane & 15);
            const int o = r * 32 + (lane >> 4) * 8;
            const short8 bh = *reinterpret_cast<const short8*>(&Bhi[o]);
            const short8 bl = *reinterpret_cast<const short8*>(&Blo[o]);
            #pragma unroll
            for (int m = 0; m < 4; ++m) {
                acc[m][n] = __builtin_amdgcn_mfma_f32_16x16x32_bf16(ah[m], bh, acc[m][n], 0, 0, 0);
                acc[m][n] = __builtin_amdgcn_mfma_f32_16x16x32_bf16(al[m], bh, acc[m][n], 0, 0, 0);
                acc[m][n] = __builtin_amdgcn_mfma_f32_16x16x32_bf16(ah[m], bl, acc[m][n], 0, 0, 0);
            }
        }
    }

    float bv[4];
    #pragma unroll
    for (int n = 0; n < 4; ++n)
        bv[n] = bias[col0 + wc * 64 + n * 16 + (lane & 15)];
    #pragma unroll
    for (int m = 0; m < 4; ++m)
        #pragma unroll
        for (int j = 0; j < 4; ++j) {
            const int gr = row0 + wr * 64 + m * 16 + (lane >> 4) * 4 + j;
            float* dst = C + (size_t)gr * N + col0 + wc * 64 + (lane & 15);
            #pragma unroll
            for (int n = 0; n < 4; ++n)
                dst[n * 16] = acc[m][n][j] + bv[n];
        }
}

// ==================================================================
// fp32 fallback GEMM — unchanged
// ==================================================================
__global__ __launch_bounds__(256)
void sgemm_bias(const float* __restrict__ A, const float* __restrict__ Bm,
                const float* __restrict__ bias, float* __restrict__ C,
                int M, int N, int K)
{
    __shared__ float As[16][136];
    __shared__ float Bs[16][136];
    const int tid = threadIdx.x;
    const int tx  = tid & 15;
    const int ty  = tid >> 4;
    const int row0 = blockIdx.y * 128;
    const int col0 = blockIdx.x * 128;
    const int ar = tid >> 2;
    const int ac = (tid & 3) << 2;
    const int br = tid >> 5;
    const int bc = (tid & 31) << 2;
    float acc[8][8];
    #pragma unroll
    for (int i = 0; i < 8; ++i)
        #pragma unroll
        for (int j = 0; j < 8; ++j) acc[i][j] = 0.f;
    for (int k0 = 0; k0 < K; k0 += 16) {
        __syncthreads();
        #pragma unroll
        for (int h = 0; h < 2; ++h) {
            const int r = ar + h * 64;
            const float* src = A + (size_t)(row0 + r) * K + k0 + ac;
            float4 v;
            if (k0 + ac + 4 <= K) {
                v = *reinterpret_cast<const float4*>(src);
            } else {
                v.x = (k0 + ac + 0 < K) ? src[0] : 0.f;
                v.y = (k0 + ac + 1 < K) ? src[1] : 0.f;
                v.z = (k0 + ac + 2 < K) ? src[2] : 0.f;
                v.w = (k0 + ac + 3 < K) ? src[3] : 0.f;
            }
            As[ac + 0][r] = v.x; As[ac + 1][r] = v.y;
            As[ac + 2][r] = v.z; As[ac + 3][r] = v.w;
        }
        #pragma unroll
        for (int h = 0; h < 2; ++h) {
            const int r = br + h * 8;
            float4 v = make_float4(0.f, 0.f, 0.f, 0.f);
            if (k0 + r < K)
                v = *reinterpret_cast<const float4*>(Bm + (size_t)(k0 + r) * N + col0 + bc);
            *reinterpret_cast<float4*>(&Bs[r][bc]) = v;
        }
        __syncthreads();
        #pragma unroll
        for (int kk = 0; kk < 16; ++kk) {
            float a[8], b[8];
            *reinterpret_cast<float4*>(&a[0]) = *reinterpret_cast<const float4*>(&As[kk][ty * 8]);
            *reinterpret_cast<float4*>(&a[4]) = *reinterpret_cast<const float4*>(&As[kk][ty * 8 + 4]);
            *reinterpret_cast<float4*>(&b[0]) = *reinterpret_cast<const float4*>(&Bs[kk][tx * 8]);
            *reinterpret_cast<float4*>(&b[4]) = *reinterpret_cast<const float4*>(&Bs[kk][tx * 8 + 4]);
            #pragma unroll
            for (int i = 0; i < 8; ++i)
                #pragma unroll
                for (int j = 0; j < 8; ++j)
                    acc[i][j] = fmaf(a[i], b[j], acc[i][j]);
        }
    }
    float bvv[8];
    *reinterpret_cast<float4*>(&bvv[0]) = *reinterpret_cast<const float4*>(bias + col0 + tx * 8);
    *reinterpret_cast<float4*>(&bvv[4]) = *reinterpret_cast<const float4*>(bias + col0 + tx * 8 + 4);
    #pragma unroll
    for (int i = 0; i < 8; ++i) {
        float* dst = C + (size_t)(row0 + ty * 8 + i) * N + col0 + tx * 8;
        float4 o0 = make_float4(acc[i][0] + bvv[0], acc[i][1] + bvv[1],
                                acc[i][2] + bvv[2], acc[i][3] + bvv[3]);
        float4 o1 = make_float4(acc[i][4] + bvv[4], acc[i][5] + bvv[5],
                                acc[i][6] + bvv[6], acc[i][7] + bvv[7]);
        *reinterpret_cast<float4*>(dst)     = o0;
        *reinterpret_cast<float4*>(dst + 4) = o1;
    }
}

// ==================================================================
// L2 normalization — unchanged
// ==================================================================
__global__ __launch_bounds__(256)
void l2norm_rows(float* __restrict__ X)
{
    __shared__ float red[4];
    const int tid = threadIdx.x;
    float4* p = reinterpret_cast<float4*>(X + (size_t)blockIdx.x * DEMB);
    float4 v = p[tid];
    float ss = v.x * v.x + v.y * v.y + v.z * v.z + v.w * v.w;
    #pragma unroll
    for (int o = 32; o; o >>= 1) ss += __shfl_xor(ss, o);
    if ((tid & 63) == 0) red[tid >> 6] = ss;
    __syncthreads();
    const float sc = rsqrtf(red[0] + red[1] + red[2] + red[3] + 1e-12f);
    v.x *= sc; v.y *= sc; v.z *= sc; v.w *= sc;
    p[tid] = v;
}

// ==================================================================
// Gram matrix + attention — unchanged from round 3
// ==================================================================
__global__ __launch_bounds__(256)
void gram_kernel(const float* __restrict__ img, float* __restrict__ G)
{
    const int b = blockIdx.x;
    const int w = threadIdx.x >> 6, lane = threadIdx.x & 63;
    const float* X = img + (size_t)b * NR * DEMB;
    float* Gb = G + (size_t)b * NR * NR;
    for (int r = w; r < NR; r += 4) {
        float c[16];
        #pragma unroll
        for (int j = 0; j < 16; ++j) c[j] = X[(size_t)r * DEMB + j * 64 + lane];
        for (int rp = r; rp < NR; ++rp) {
            float p = 0.f;
            #pragma unroll
            for (int j = 0; j < 16; ++j)
                p = fmaf(c[j], X[(size_t)rp * DEMB + j * 64 + lane], p);
            p = wred(p);
            if (lane == 0) { Gb[r * NR + rp] = p; Gb[rp * NR + r] = p; }
        }
    }
}

#define CH 6
__global__ __launch_bounds__(256)
void scan_attn2(const float* __restrict__ img, const float* __restrict__ cap,
                const float* __restrict__ G, const int* __restrict__ lens,
                float* __restrict__ out)
{
    __shared__ float simg[CH * 1024];
    __shared__ float sS[15][37];
    __shared__ float sE[15][37];
    __shared__ float sG[36][37];
    __shared__ float scap[15];
    __shared__ float wsum[4];

    const int g = blockIdx.x;
    const int b = blockIdx.y;
    const int tid = threadIdx.x, w = tid >> 6, lane = tid & 63;
    const int len = lens[b];
    const int l0 = g * 15;
    const float* imgb = img + (size_t)b * NR * DEMB;
    const float* capb = cap + (size_t)b * NL * DEMB;

    for (int t = tid; t < NR * NR; t += 256)
        sG[t / 36][t % 36] = G[(size_t)b * (NR * NR) + t];

    for (int rc = 0; rc < 6; ++rc) {
        __syncthreads();
        {
            const float4* src = reinterpret_cast<const float4*>(imgb + (size_t)rc * CH * DEMB);
            float4* dst = reinterpret_cast<float4*>(simg);
            #pragma unroll
            for (int t = 0; t < 6; ++t) dst[tid + t * 256] = src[tid + t * 256];
        }
        __syncthreads();
        for (int i = w; i < 15; i += 4) {
            const int l = l0 + i;
            float c[16];
            #pragma unroll
            for (int j = 0; j < 16; ++j) c[j] = capb[(size_t)l * DEMB + j * 64 + lane];
            if (rc == 0) {
                float s2 = 0.f;
                #pragma unroll
                for (int j = 0; j < 16; ++j) s2 = fmaf(c[j], c[j], s2);
                s2 = wred(s2);
                if (lane == 0) scap[i] = s2;
            }
            #pragma unroll
            for (int r = 0; r < CH; ++r) {
                float p = 0.f;
                #pragma unroll
                for (int j = 0; j < 16; ++j)
                    p = fmaf(c[j], simg[r * 1024 + j * 64 + lane], p);
                p = wred(p);
                if (lane == 0) sS[i][rc * CH + r] = p;
            }
        }
    }

    float wacc = 0.f;
    for (int i = w; i < 15; i += 4) {
        const int l = l0 + i;
        const float sv = (lane < NR) ? sS[i][lane] : -1e30f;
        float m = sv;
        #pragma unroll
        for (int o = 32; o; o >>= 1) m = fmaxf(m, __shfl_xor(m, o));
        const float e = (lane < NR) ? __expf(9.f * (sv - m)) : 0.f;
        if (lane < NR) sE[i][lane] = e;
        float num = 0.f, aq = 0.f;
        if (lane < NR) {
            float q = 0.f;
            #pragma unroll
            for (int rp = 0; rp < NR; ++rp)
                q = fmaf(sG[lane][rp], sE[i][rp], q);
            num = e * sv;
            aq  = e * q;
        }
        num = wred(num);
        aq  = wred(aq);
        if (lane == 0 && l < len) {
            const float ncap = fmaxf(sqrtf(scap[i]), 1e-8f);
            const float natt = fmaxf(sqrtf(aq), 1e-8f);
            wacc += num / (ncap * natt);
        }
    }
    if (lane == 0) wsum[w] = wacc;
    __syncthreads();
    if (tid == 0) {
        const float s = wsum[0] + wsum[1] + wsum[2] + wsum[3];
        atomicAdd(out + b, s / (float)len);
    }
}

// ==================================================================
extern "C" void kernel_launch(void* const* d_in, const int* in_sizes, int n_in,
                              void* d_out, int out_size, void* d_ws, size_t ws_size,
                              hipStream_t stream)
{
    const float* images   = (const float*)d_in[0];
    const float* captions = (const float*)d_in[1];
    const int*   lens     = (const int*)  d_in[2];
    const float* W_img    = (const float*)d_in[3];
    const float* b_img    = (const float*)d_in[4];
    const float* W_txt    = (const float*)d_in[5];
    const float* b_txt    = (const float*)d_in[6];
    float*       out      = (float*)d_out;

    const size_t EMB  = (size_t)(NB * NR + NB * NL) * DEMB * 4;   // 100.7 MB
    const size_t WIT  = (size_t)DEMB * DIMG * 2;                  // 4 MiB per half
    const size_t WTT  = (size_t)DEMB * KPC * 2;
    const size_t AIT  = (size_t)NB * NR * DIMG * 2;               // 37.75 MB per half
    const size_t ACT  = (size_t)NB * NL * KPC * 2;                // 9.83 MB per half
    const size_t G_B  = (size_t)NB * NR * NR * 4;                 // 1.33 MB

    char* base = (char*)d_ws;
    float* img_embs = (float*)base;
    float* cap_embs = (float*)(base + (size_t)NB * NR * DEMB * 4);

    size_t o = EMB;
    short* WimgT_hi = (short*)(base + o); o += WIT;
    short* WimgT_lo = (short*)(base + o); o += WIT;
    short* WtxtT_hi = (short*)(base + o); o += WTT;
    short* WtxtT_lo = (short*)(base + o); o += WTT;
    const size_t NEED1 = o;                     // ~110.4 MB (round-3 path)
    short* AimgHi = (short*)(base + o); o += AIT;
    short* AimgLo = (short*)(base + o); o += AIT;
    short* AcapHi = (short*)(base + o); o += ACT;
    short* AcapLo = (short*)(base + o); o += ACT;
    float* Gm2    = (float*)(base + o); o += G_B;
    const size_t NEED2 = o;                     // ~207 MB (pre-split path)
    float* Gm1    = (float*)(base + EMB);       // overlays spent W region

    float* Gm;
    if (ws_size >= NEED2) {
        Gm = Gm2;
        split_transpose<<<dim3(DIMG / 64, DEMB / 64), 256, 0, stream>>>(
            W_img, WimgT_hi, WimgT_lo, DIMG, DEMB, DIMG);
        split_transpose<<<dim3(KPC / 64, DEMB / 64), 256, 0, stream>>>(
            W_txt, WtxtT_hi, WtxtT_lo, DWRD, DEMB, KPC);
        split_rows<<<(NB * NR * (DIMG / 8) + 255) / 256, 256, 0, stream>>>(
            images, AimgHi, AimgLo, NB * NR, DIMG, DIMG);
        split_rows<<<(NB * NL * (KPC / 8) + 255) / 256, 256, 0, stream>>>(
            captions, AcapHi, AcapLo, NB * NL, DWRD, KPC);

        gemm_presplit<<<dim3(DEMB / 128, (NB * NR) / 128), 256, 0, stream>>>(
            AimgHi, AimgLo, WimgT_hi, WimgT_lo, b_img, img_embs, NB * NR, DEMB, DIMG);
        gemm_presplit<<<dim3(DEMB / 128, (NB * NL) / 128), 256, 0, stream>>>(
            AcapHi, AcapLo, WtxtT_hi, WtxtT_lo, b_txt, cap_embs, NB * NL, DEMB, KPC);
    } else if (ws_size >= NEED1) {
        Gm = Gm1;
        split_transpose<<<dim3(DIMG / 64, DEMB / 64), 256, 0, stream>>>(
            W_img, WimgT_hi, WimgT_lo, DIMG, DEMB, DIMG);
        split_transpose<<<dim3(KPC / 64, DEMB / 64), 256, 0, stream>>>(
            W_txt, WtxtT_hi, WtxtT_lo, DWRD, DEMB, KPC);
        gemm_asplit<<<dim3(DEMB / 128, (NB * NR) / 128), 256, 0, stream>>>(
            images, WimgT_hi, WimgT_lo, b_img, img_embs, NB * NR, DEMB, DIMG, DIMG);
        gemm_asplit<<<dim3(DEMB / 128, (NB * NL) / 128), 256, 0, stream>>>(
            captions, WtxtT_hi, WtxtT_lo, b_txt, cap_embs, NB * NL, DEMB, DWRD, KPC);
    } else {
        Gm = Gm1;
        sgemm_bias<<<dim3(DEMB / 128, (NB * NR) / 128), 256, 0, stream>>>(
            images, W_img, b_img, img_embs, NB * NR, DEMB, DIMG);
        sgemm_bias<<<dim3(DEMB / 128, (NB * NL) / 128), 256, 0, stream>>>(
            captions, W_txt, b_txt, cap_embs, NB * NL, DEMB, DWRD);
    }

    l2norm_rows<<<NB * NR, 256, 0, stream>>>(img_embs);
    l2norm_rows<<<NB * NL, 256, 0, stream>>>(cap_embs);

    gram_kernel<<<NB, 256, 0, stream>>>(img_embs, Gm);

    hipMemsetAsync(d_out, 0, NB * sizeof(float), stream);
    scan_attn2<<<dim3(4, NB), 256, 0, stream>>>(img_embs, cap_embs, Gm, lens, out);
}

// Round 7
// 491.574 us; speedup vs baseline: 2.2849x; 1.2085x over previous
//
#include <hip/hip_runtime.h>
#include <math.h>

// Shapes (fixed by the problem)
#define NB   256
#define NR   36
#define NL   60
#define DIMG 2048
#define DWRD 300
#define DEMB 1024
#define KPC  320   // captions K padded

typedef __attribute__((ext_vector_type(8))) short short8;
typedef __attribute__((ext_vector_type(4))) short short4v;
typedef __attribute__((ext_vector_type(4))) float f32x4;

#define AS1 __attribute__((address_space(1)))
#define AS3 __attribute__((address_space(3)))

__device__ __forceinline__ unsigned short bf16_rne(float x) {
    unsigned u = __builtin_bit_cast(unsigned, x);
    unsigned r = u + 0x7FFFu + ((u >> 16) & 1u);
    return (unsigned short)(r >> 16);
}
__device__ __forceinline__ float bf16_to_f(unsigned short h) {
    unsigned u = ((unsigned)h) << 16;
    return __builtin_bit_cast(float, u);
}

__device__ __forceinline__ float wred(float v)
{
    #pragma unroll
    for (int o = 32; o; o >>= 1) v += __shfl_xor(v, o);
    return v;
}

// ==================================================================
// W (K x N f32) -> Wt_hi/Wt_lo (N x KP bf16), zero-padded.
// ==================================================================
__global__ __launch_bounds__(256)
void split_transpose(const float* __restrict__ W, short* __restrict__ Thi,
                     short* __restrict__ Tlo, int K, int N, int KP)
{
    __shared__ float T[64][68];
    const int t = threadIdx.x;
    const int k0 = blockIdx.x * 64, n0 = blockIdx.y * 64;
    #pragma unroll
    for (int q = 0; q < 4; ++q) {
        const int r = (t >> 4) + q * 16;
        const int c4 = (t & 15) * 4;
        float4 v = make_float4(0.f, 0.f, 0.f, 0.f);
        if (k0 + r < K)
            v = *reinterpret_cast<const float4*>(W + (size_t)(k0 + r) * N + n0 + c4);
        T[r][c4] = v.x; T[r][c4 + 1] = v.y; T[r][c4 + 2] = v.z; T[r][c4 + 3] = v.w;
    }
    __syncthreads();
    #pragma unroll
    for (int q = 0; q < 4; ++q) {
        const int nl = (t >> 4) + q * 16;
        const int kc = (t & 15) * 4;
        short hs[4] __attribute__((aligned(8)));
        short ls[4] __attribute__((aligned(8)));
        #pragma unroll
        for (int i = 0; i < 4; ++i) {
            const float x = T[kc + i][nl];
            const unsigned short hb = bf16_rne(x);
            hs[i] = (short)hb;
            ls[i] = (short)bf16_rne(x - bf16_to_f(hb));
        }
        const size_t o = (size_t)(n0 + nl) * KP + k0 + kc;
        *reinterpret_cast<short4v*>(Thi + o) = *reinterpret_cast<short4v*>(hs);
        *reinterpret_cast<short4v*>(Tlo + o) = *reinterpret_cast<short4v*>(ls);
    }
}

// ==================================================================
// Row-major A (M x K f32) -> A_hi/A_lo (M x KP bf16), zero-padded.
// ==================================================================
__global__ __launch_bounds__(256)
void split_rows(const float* __restrict__ A, short* __restrict__ Hi,
                short* __restrict__ Lo, int M, int K, int KP)
{
    const int gp  = KP >> 3;
    const int idx = blockIdx.x * 256 + threadIdx.x;
    if (idx >= M * gp) return;
    const int row = idx / gp;
    const int g8  = (idx - row * gp) * 8;

    float v[8] __attribute__((aligned(16)));
    const float* src = A + (size_t)row * K + g8;
    if (g8 + 8 <= K) {
        *reinterpret_cast<float4*>(&v[0]) = *reinterpret_cast<const float4*>(src);
        *reinterpret_cast<float4*>(&v[4]) = *reinterpret_cast<const float4*>(src + 4);
    } else {
        #pragma unroll
        for (int i = 0; i < 8; ++i) v[i] = (g8 + i < K) ? src[i] : 0.f;
    }
    short hs[8] __attribute__((aligned(16)));
    short ls[8] __attribute__((aligned(16)));
    #pragma unroll
    for (int i = 0; i < 8; ++i) {
        const unsigned short hb = bf16_rne(v[i]);
        hs[i] = (short)hb;
        ls[i] = (short)bf16_rne(v[i] - bf16_to_f(hb));
    }
    const size_t o = (size_t)row * KP + g8;
    *reinterpret_cast<short8*>(Hi + o) = *reinterpret_cast<short8*>(hs);
    *reinterpret_cast<short8*>(Lo + o) = *reinterpret_cast<short8*>(ls);
}

// ==================================================================
// 96x128 tile GEMM, pre-split bf16 operands, global_load_lds staging,
// bijective XCD swizzle (requires gridDim.x % 8 == 0; holds: 768/1280).
// acc += Ah*Bh + Al*Bh + Ah*Bl.
// ==================================================================
#define BM 96
#define BN 128
__global__ __launch_bounds__(256)
void gemm_presplit96(const short* __restrict__ Ahg, const short* __restrict__ Alg,
                     const short* __restrict__ Bhg, const short* __restrict__ Blg,
                     const float* __restrict__ bias, float* __restrict__ C,
                     int M, int N, int KP)
{
    __shared__ short Ahi[BM * 32], Alo[BM * 32];   // 6 KB each
    __shared__ short Bhi[BN * 32], Blo[BN * 32];   // 8 KB each (28 KB total)

    const int tid  = threadIdx.x;
    const int w    = tid >> 6, lane = tid & 63;
    const int wr   = w >> 1,   wc   = w & 1;

    // XCD-aware bijective swizzle: 8 consecutive-orig blocks -> same XCD chunk
    const int nwg  = (int)gridDim.x;
    const int cpx  = nwg >> 3;
    const int bid  = (int)blockIdx.x;
    const int swz  = (bid & 7) * cpx + (bid >> 3);
    const int ncol = N / BN;
    const int col0 = (swz % ncol) * BN;
    const int row0 = (swz / ncol) * BM;

    f32x4 acc[3][4];
    #pragma unroll
    for (int m = 0; m < 3; ++m)
        #pragma unroll
        for (int n = 0; n < 4; ++n)
            acc[m][n] = (f32x4){0.f, 0.f, 0.f, 0.f};

    for (int k0 = 0; k0 < KP; k0 += 32) {
        __syncthreads();
        // stage A: 384 16B-chunks per matrix (wave-uniform bounds)
        for (int c = tid; c < (BM * 32) / 8; c += 256) {
            const int r = c >> 2, k8 = (c & 3) * 8;
            const size_t ga = (size_t)(row0 + r) * KP + k0 + k8;
            __builtin_amdgcn_global_load_lds((AS1 void*)(Ahg + ga),
                                             (AS3 void*)(Ahi + c * 8), 16, 0, 0);
            __builtin_amdgcn_global_load_lds((AS1 void*)(Alg + ga),
                                             (AS3 void*)(Alo + c * 8), 16, 0, 0);
        }
        // stage B: 512 16B-chunks per matrix
        for (int c = tid; c < (BN * 32) / 8; c += 256) {
            const int r = c >> 2, k8 = (c & 3) * 8;
            const size_t gb = (size_t)(col0 + r) * KP + k0 + k8;
            __builtin_amdgcn_global_load_lds((AS1 void*)(Bhg + gb),
                                             (AS3 void*)(Bhi + c * 8), 16, 0, 0);
            __builtin_amdgcn_global_load_lds((AS1 void*)(Blg + gb),
                                             (AS3 void*)(Blo + c * 8), 16, 0, 0);
        }
        __syncthreads();

        short8 ah[3], al[3];
        #pragma unroll
        for (int m = 0; m < 3; ++m) {
            const int r = wr * 48 + m * 16 + (lane & 15);
            const int o = r * 32 + (lane >> 4) * 8;
            ah[m] = *reinterpret_cast<const short8*>(&Ahi[o]);
            al[m] = *reinterpret_cast<const short8*>(&Alo[o]);
        }
        #pragma unroll
        for (int n = 0; n < 4; ++n) {
            const int r = wc * 64 + n * 16 + (lane & 15);
            const int o = r * 32 + (lane >> 4) * 8;
            const short8 bh = *reinterpret_cast<const short8*>(&Bhi[o]);
            const short8 bl = *reinterpret_cast<const short8*>(&Blo[o]);
            #pragma unroll
            for (int m = 0; m < 3; ++m) {
                acc[m][n] = __builtin_amdgcn_mfma_f32_16x16x32_bf16(ah[m], bh, acc[m][n], 0, 0, 0);
                acc[m][n] = __builtin_amdgcn_mfma_f32_16x16x32_bf16(al[m], bh, acc[m][n], 0, 0, 0);
                acc[m][n] = __builtin_amdgcn_mfma_f32_16x16x32_bf16(ah[m], bl, acc[m][n], 0, 0, 0);
            }
        }
    }

    float bv[4];
    #pragma unroll
    for (int n = 0; n < 4; ++n)
        bv[n] = bias[col0 + wc * 64 + n * 16 + (lane & 15)];
    #pragma unroll
    for (int m = 0; m < 3; ++m)
        #pragma unroll
        for (int j = 0; j < 4; ++j) {
            const int gr = row0 + wr * 48 + m * 16 + (lane >> 4) * 4 + j;
            float* dst = C + (size_t)gr * N + col0 + wc * 64 + (lane & 15);
            #pragma unroll
            for (int n = 0; n < 4; ++n)
                dst[n * 16] = acc[m][n][j] + bv[n];
        }
}

// ==================================================================
// Fallback: on-the-fly A split GEMM (mid ws) — unchanged
// ==================================================================
__global__ __launch_bounds__(256)
void gemm_asplit(const float* __restrict__ A, const short* __restrict__ Bthi,
                 const short* __restrict__ Btlo, const float* __restrict__ bias,
                 float* __restrict__ C, int M, int N, int K, int KP)
{
    __shared__ short Ahi[128 * 32], Alo[128 * 32];
    __shared__ short Bhi[128 * 32], Blo[128 * 32];

    const int tid  = threadIdx.x;
    const int w    = tid >> 6, lane = tid & 63;
    const int wr   = w >> 1,   wc   = w & 1;
    const int row0 = blockIdx.y * 128, col0 = blockIdx.x * 128;

    f32x4 acc[4][4];
    #pragma unroll
    for (int m = 0; m < 4; ++m)
        #pragma unroll
        for (int n = 0; n < 4; ++n)
            acc[m][n] = (f32x4){0.f, 0.f, 0.f, 0.f};

    for (int k0 = 0; k0 < KP; k0 += 32) {
        __syncthreads();
        #pragma unroll
        for (int h = 0; h < 2; ++h) {
            const int c = tid + h * 256;
            const int r = c >> 2;
            const int ke = (c & 3) * 8;
            const int gk = k0 + ke;
            const float* src = A + (size_t)(row0 + r) * K + gk;
            float v[8] __attribute__((aligned(16)));
            if (gk + 8 <= K) {
                *reinterpret_cast<float4*>(&v[0]) = *reinterpret_cast<const float4*>(src);
                *reinterpret_cast<float4*>(&v[4]) = *reinterpret_cast<const float4*>(src + 4);
            } else {
                #pragma unroll
                for (int i = 0; i < 8; ++i)
                    v[i] = (gk + i < K) ? src[i] : 0.f;
            }
            short hs[8] __attribute__((aligned(16)));
            short ls[8] __attribute__((aligned(16)));
            #pragma unroll
            for (int i = 0; i < 8; ++i) {
                const unsigned short hb = bf16_rne(v[i]);
                hs[i] = (short)hb;
                ls[i] = (short)bf16_rne(v[i] - bf16_to_f(hb));
            }
            *reinterpret_cast<short8*>(&Ahi[c * 8]) = *reinterpret_cast<short8*>(hs);
            *reinterpret_cast<short8*>(&Alo[c * 8]) = *reinterpret_cast<short8*>(ls);
        }
        #pragma unroll
        for (int j = 0; j < 2; ++j) {
            const int s = w * 2 + j;
            const int n = 16 * s + (lane >> 2);
            const size_t go = (size_t)(col0 + n) * KP + k0 + (lane & 3) * 8;
            __builtin_amdgcn_global_load_lds((AS1 void*)(Bthi + go),
                                             (AS3 void*)(Bhi + s * 512), 16, 0, 0);
            __builtin_amdgcn_global_load_lds((AS1 void*)(Btlo + go),
                                             (AS3 void*)(Blo + s * 512), 16, 0, 0);
        }
        __syncthreads();

        short8 ah[4], al[4];
        #pragma unroll
        for (int m = 0; m < 4; ++m) {
            const int r = wr * 64 + m * 16 + (lane & 15);
            const int o = r * 32 + (lane >> 4) * 8;
            ah[m] = *reinterpret_cast<const short8*>(&Ahi[o]);
            al[m] = *reinterpret_cast<const short8*>(&Alo[o]);
        }
        #pragma unroll
        for (int n = 0; n < 4; ++n) {
            const int r = wc * 64 + n * 16 + (lane & 15);
            const int o = r * 32 + (lane >> 4) * 8;
            const short8 bh = *reinterpret_cast<const short8*>(&Bhi[o]);
            const short8 bl = *reinterpret_cast<const short8*>(&Blo[o]);
            #pragma unroll
            for (int m = 0; m < 4; ++m) {
                acc[m][n] = __builtin_amdgcn_mfma_f32_16x16x32_bf16(ah[m], bh, acc[m][n], 0, 0, 0);
                acc[m][n] = __builtin_amdgcn_mfma_f32_16x16x32_bf16(al[m], bh, acc[m][n], 0, 0, 0);
                acc[m][n] = __builtin_amdgcn_mfma_f32_16x16x32_bf16(ah[m], bl, acc[m][n], 0, 0, 0);
            }
        }
    }

    float bv[4];
    #pragma unroll
    for (int n = 0; n < 4; ++n)
        bv[n] = bias[col0 + wc * 64 + n * 16 + (lane & 15)];
    #pragma unroll
    for (int m = 0; m < 4; ++m)
        #pragma unroll
        for (int j = 0; j < 4; ++j) {
            const int gr = row0 + wr * 64 + m * 16 + (lane >> 4) * 4 + j;
            float* dst = C + (size_t)gr * N + col0 + wc * 64 + (lane & 15);
            #pragma unroll
            for (int n = 0; n < 4; ++n)
                dst[n * 16] = acc[m][n][j] + bv[n];
        }
}

// ==================================================================
// Fallback fp32 GEMM — unchanged
// ==================================================================
__global__ __launch_bounds__(256)
void sgemm_bias(const float* __restrict__ A, const float* __restrict__ Bm,
                const float* __restrict__ bias, float* __restrict__ C,
                int M, int N, int K)
{
    __shared__ float As[16][136];
    __shared__ float Bs[16][136];
    const int tid = threadIdx.x;
    const int tx  = tid & 15;
    const int ty  = tid >> 4;
    const int row0 = blockIdx.y * 128;
    const int col0 = blockIdx.x * 128;
    const int ar = tid >> 2;
    const int ac = (tid & 3) << 2;
    const int br = tid >> 5;
    const int bc = (tid & 31) << 2;
    float acc[8][8];
    #pragma unroll
    for (int i = 0; i < 8; ++i)
        #pragma unroll
        for (int j = 0; j < 8; ++j) acc[i][j] = 0.f;
    for (int k0 = 0; k0 < K; k0 += 16) {
        __syncthreads();
        #pragma unroll
        for (int h = 0; h < 2; ++h) {
            const int r = ar + h * 64;
            const float* src = A + (size_t)(row0 + r) * K + k0 + ac;
            float4 v;
            if (k0 + ac + 4 <= K) {
                v = *reinterpret_cast<const float4*>(src);
            } else {
                v.x = (k0 + ac + 0 < K) ? src[0] : 0.f;
                v.y = (k0 + ac + 1 < K) ? src[1] : 0.f;
                v.z = (k0 + ac + 2 < K) ? src[2] : 0.f;
                v.w = (k0 + ac + 3 < K) ? src[3] : 0.f;
            }
            As[ac + 0][r] = v.x; As[ac + 1][r] = v.y;
            As[ac + 2][r] = v.z; As[ac + 3][r] = v.w;
        }
        #pragma unroll
        for (int h = 0; h < 2; ++h) {
            const int r = br + h * 8;
            float4 v = make_float4(0.f, 0.f, 0.f, 0.f);
            if (k0 + r < K)
                v = *reinterpret_cast<const float4*>(Bm + (size_t)(k0 + r) * N + col0 + bc);
            *reinterpret_cast<float4*>(&Bs[r][bc]) = v;
        }
        __syncthreads();
        #pragma unroll
        for (int kk = 0; kk < 16; ++kk) {
            float a[8], b[8];
            *reinterpret_cast<float4*>(&a[0]) = *reinterpret_cast<const float4*>(&As[kk][ty * 8]);
            *reinterpret_cast<float4*>(&a[4]) = *reinterpret_cast<const float4*>(&As[kk][ty * 8 + 4]);
            *reinterpret_cast<float4*>(&b[0]) = *reinterpret_cast<const float4*>(&Bs[kk][tx * 8]);
            *reinterpret_cast<float4*>(&b[4]) = *reinterpret_cast<const float4*>(&Bs[kk][tx * 8 + 4]);
            #pragma unroll
            for (int i = 0; i < 8; ++i)
                #pragma unroll
                for (int j = 0; j < 8; ++j)
                    acc[i][j] = fmaf(a[i], b[j], acc[i][j]);
        }
    }
    float bvv[8];
    *reinterpret_cast<float4*>(&bvv[0]) = *reinterpret_cast<const float4*>(bias + col0 + tx * 8);
    *reinterpret_cast<float4*>(&bvv[4]) = *reinterpret_cast<const float4*>(bias + col0 + tx * 8 + 4);
    #pragma unroll
    for (int i = 0; i < 8; ++i) {
        float* dst = C + (size_t)(row0 + ty * 8 + i) * N + col0 + tx * 8;
        float4 o0 = make_float4(acc[i][0] + bvv[0], acc[i][1] + bvv[1],
                                acc[i][2] + bvv[2], acc[i][3] + bvv[3]);
        float4 o1 = make_float4(acc[i][4] + bvv[4], acc[i][5] + bvv[5],
                                acc[i][6] + bvv[6], acc[i][7] + bvv[7]);
        *reinterpret_cast<float4*>(dst)     = o0;
        *reinterpret_cast<float4*>(dst + 4) = o1;
    }
}

// ==================================================================
// Gram on RAW embeddings: G~ = img @ img^T. Grid (NB, 9), 4 rows/block.
// ==================================================================
__global__ __launch_bounds__(256)
void gram_kernel2(const float* __restrict__ img, float* __restrict__ G)
{
    const int b = blockIdx.x;
    const int w = threadIdx.x >> 6, lane = threadIdx.x & 63;
    const int r = blockIdx.y * 4 + w;    // 0..35
    const float* X = img + (size_t)b * NR * DEMB;
    float* Gb = G + (size_t)b * NR * NR;

    float c[16];
    #pragma unroll
    for (int j = 0; j < 16; ++j) c[j] = X[(size_t)r * DEMB + j * 64 + lane];
    for (int rp = 0; rp < NR; ++rp) {
        float p = 0.f;
        #pragma unroll
        for (int j = 0; j < 16; ++j)
            p = fmaf(c[j], X[(size_t)rp * DEMB + j * 64 + lane], p);
        p = wred(p);
        if (lane == 0) Gb[r * NR + rp] = p;
    }
}

// ==================================================================
// Attention on RAW embeddings, normalization folded on read.
// Grid (4 word-groups, NB). S~ dots vs raw img; S = S~*fc*fi;
// G_norm = G~*fi_r*fi_rp; ||att||^2 = w^T G_norm w; atomicAdd.
// ==================================================================
#define CH 6
__global__ __launch_bounds__(256)
void scan_attn3(const float* __restrict__ img, const float* __restrict__ cap,
                const float* __restrict__ G, const int* __restrict__ lens,
                float* __restrict__ out)
{
    __shared__ float simg[CH * 1024];
    __shared__ float sS[15][37];
    __shared__ float sE[15][37];
    __shared__ float sG[36][37];
    __shared__ float sfi[36];
    __shared__ float scap[15];
    __shared__ float wsum[4];

    const int g = blockIdx.x;
    const int b = blockIdx.y;
    const int tid = threadIdx.x, w = tid >> 6, lane = tid & 63;
    const int len = lens[b];
    const int l0 = g * 15;
    const float* imgb = img + (size_t)b * NR * DEMB;
    const float* capb = cap + (size_t)b * NL * DEMB;
    const float* Gb   = G + (size_t)b * (NR * NR);

    // img-row inverse norms from the Gram diagonal
    if (tid < NR) sfi[tid] = rsqrtf(Gb[tid * NR + tid] + 1e-12f);
    __syncthreads();
    // normalized Gram into LDS
    for (int t = tid; t < NR * NR; t += 256) {
        const int r = t / 36, c = t - r * 36;
        sG[r][c] = Gb[t] * sfi[r] * sfi[c];
    }

    // ---- Phase 1: raw similarity scores over 6 chunks of 6 img rows ----
    for (int rc = 0; rc < 6; ++rc) {
        __syncthreads();
        {
            const float4* src = reinterpret_cast<const float4*>(imgb + (size_t)rc * CH * DEMB);
            float4* dst = reinterpret_cast<float4*>(simg);
            #pragma unroll
            for (int t = 0; t < 6; ++t) dst[tid + t * 256] = src[tid + t * 256];
        }
        __syncthreads();
        for (int i = w; i < 15; i += 4) {
            const int l = l0 + i;
            float c[16];
            #pragma unroll
            for (int j = 0; j < 16; ++j) c[j] = capb[(size_t)l * DEMB + j * 64 + lane];
            if (rc == 0) {
                float s2 = 0.f;
                #pragma unroll
                for (int j = 0; j < 16; ++j) s2 = fmaf(c[j], c[j], s2);
                s2 = wred(s2);
                if (lane == 0) scap[i] = s2;
            }
            #pragma unroll
            for (int r = 0; r < CH; ++r) {
                float p = 0.f;
                #pragma unroll
                for (int j = 0; j < 16; ++j)
                    p = fmaf(c[j], simg[r * 1024 + j * 64 + lane], p);
                p = wred(p);
                if (lane == 0) sS[i][rc * CH + r] = p;
            }
        }
    }

    // ---- Finalize (wave-local) ----
    float wacc = 0.f;
    for (int i = w; i < 15; i += 4) {
        const int l = l0 + i;
        const float fc = rsqrtf(scap[i] + 1e-12f);
        const float sv = (lane < NR) ? sS[i][lane] * fc * sfi[lane] : -1e30f;
        float m = sv;
        #pragma unroll
        for (int o = 32; o; o >>= 1) m = fmaxf(m, __shfl_xor(m, o));
        const float e = (lane < NR) ? __expf(9.f * (sv - m)) : 0.f;
        if (lane < NR) sE[i][lane] = e;
        float num = 0.f, aq = 0.f;
        if (lane < NR) {
            float q = 0.f;
            #pragma unroll
            for (int rp = 0; rp < NR; ++rp)
                q = fmaf(sG[lane][rp], sE[i][rp], q);
            num = e * sv;
            aq  = e * q;
        }
        num = wred(num);
        aq  = wred(aq);
        if (lane == 0 && l < len) {
            const float nu   = fmaxf(sqrtf(scap[i]) * fc, 1e-8f);
            const float natt = fmaxf(sqrtf(aq), 1e-8f);
            wacc += num / (nu * natt);
        }
    }
    if (lane == 0) wsum[w] = wacc;
    __syncthreads();
    if (tid == 0) {
        const float s = wsum[0] + wsum[1] + wsum[2] + wsum[3];
        atomicAdd(out + b, s / (float)len);
    }
}

// ==================================================================
extern "C" void kernel_launch(void* const* d_in, const int* in_sizes, int n_in,
                              void* d_out, int out_size, void* d_ws, size_t ws_size,
                              hipStream_t stream)
{
    const float* images   = (const float*)d_in[0];
    const float* captions = (const float*)d_in[1];
    const int*   lens     = (const int*)  d_in[2];
    const float* W_img    = (const float*)d_in[3];
    const float* b_img    = (const float*)d_in[4];
    const float* W_txt    = (const float*)d_in[5];
    const float* b_txt    = (const float*)d_in[6];
    float*       out      = (float*)d_out;

    const size_t EMB  = (size_t)(NB * NR + NB * NL) * DEMB * 4;   // 100.7 MB
    const size_t WIT  = (size_t)DEMB * DIMG * 2;
    const size_t WTT  = (size_t)DEMB * KPC * 2;
    const size_t AIT  = (size_t)NB * NR * DIMG * 2;
    const size_t ACT  = (size_t)NB * NL * KPC * 2;
    const size_t G_B  = (size_t)NB * NR * NR * 4;

    char* base = (char*)d_ws;
    float* img_embs = (float*)base;
    float* cap_embs = (float*)(base + (size_t)NB * NR * DEMB * 4);

    size_t o = EMB;
    short* WimgT_hi = (short*)(base + o); o += WIT;
    short* WimgT_lo = (short*)(base + o); o += WIT;
    short* WtxtT_hi = (short*)(base + o); o += WTT;
    short* WtxtT_lo = (short*)(base + o); o += WTT;
    const size_t NEED1 = o;
    short* AimgHi = (short*)(base + o); o += AIT;
    short* AimgLo = (short*)(base + o); o += AIT;
    short* AcapHi = (short*)(base + o); o += ACT;
    short* AcapLo = (short*)(base + o); o += ACT;
    float* Gm2    = (float*)(base + o); o += G_B;
    const size_t NEED2 = o;
    float* Gm1    = (float*)(base + EMB);

    float* Gm;
    if (ws_size >= NEED2) {
        Gm = Gm2;
        split_transpose<<<dim3(DIMG / 64, DEMB / 64), 256, 0, stream>>>(
            W_img, WimgT_hi, WimgT_lo, DIMG, DEMB, DIMG);
        split_transpose<<<dim3(KPC / 64, DEMB / 64), 256, 0, stream>>>(
            W_txt, WtxtT_hi, WtxtT_lo, DWRD, DEMB, KPC);
        split_rows<<<(NB * NR * (DIMG / 8) + 255) / 256, 256, 0, stream>>>(
            images, AimgHi, AimgLo, NB * NR, DIMG, DIMG);
        split_rows<<<(NB * NL * (KPC / 8) + 255) / 256, 256, 0, stream>>>(
            captions, AcapHi, AcapLo, NB * NL, DWRD, KPC);

        gemm_presplit96<<<(DEMB / BN) * ((NB * NR) / BM), 256, 0, stream>>>(
            AimgHi, AimgLo, WimgT_hi, WimgT_lo, b_img, img_embs, NB * NR, DEMB, DIMG);
        gemm_presplit96<<<(DEMB / BN) * ((NB * NL) / BM), 256, 0, stream>>>(
            AcapHi, AcapLo, WtxtT_hi, WtxtT_lo, b_txt, cap_embs, NB * NL, DEMB, KPC);
    } else if (ws_size >= NEED1) {
        Gm = Gm1;
        split_transpose<<<dim3(DIMG / 64, DEMB / 64), 256, 0, stream>>>(
            W_img, WimgT_hi, WimgT_lo, DIMG, DEMB, DIMG);
        split_transpose<<<dim3(KPC / 64, DEMB / 64), 256, 0, stream>>>(
            W_txt, WtxtT_hi, WtxtT_lo, DWRD, DEMB, KPC);
        gemm_asplit<<<dim3(DEMB / 128, (NB * NR) / 128), 256, 0, stream>>>(
            images, WimgT_hi, WimgT_lo, b_img, img_embs, NB * NR, DEMB, DIMG, DIMG);
        gemm_asplit<<<dim3(DEMB / 128, (NB * NL) / 128), 256, 0, stream>>>(
            captions, WtxtT_hi, WtxtT_lo, b_txt, cap_embs, NB * NL, DEMB, DWRD, KPC);
    } else {
        Gm = Gm1;
        sgemm_bias<<<dim3(DEMB / 128, (NB * NR) / 128), 256, 0, stream>>>(
            images, W_img, b_img, img_embs, NB * NR, DEMB, DIMG);
        sgemm_bias<<<dim3(DEMB / 128, (NB * NL) / 128), 256, 0, stream>>>(
            captions, W_txt, b_txt, cap_embs, NB * NL, DEMB, DWRD);
    }

    // Gram on raw embeddings (norms folded downstream; l2norm kernels removed)
    gram_kernel2<<<dim3(NB, 9), 256, 0, stream>>>(img_embs, Gm);

    hipMemsetAsync(d_out, 0, NB * sizeof(float), stream);
    scan_attn3<<<dim3(4, NB), 256, 0, stream>>>(img_embs, cap_embs, Gm, lens, out);
}

// Round 8
// 385.447 us; speedup vs baseline: 2.9141x; 1.2753x over previous
//
#include <hip/hip_runtime.h>
#include <math.h>

// Shapes (fixed by the problem)
#define NB   256
#define NR   36
#define NL   60
#define DIMG 2048
#define DWRD 300
#define DEMB 1024
#define KPC  320   // captions K padded
#define PRI  48    // img rows padded (per batch)
#define PRC  64    // cap rows padded (per batch)

typedef __attribute__((ext_vector_type(8))) short short8;
typedef __attribute__((ext_vector_type(4))) short short4v;
typedef __attribute__((ext_vector_type(4))) float f32x4;

#define AS1 __attribute__((address_space(1)))
#define AS3 __attribute__((address_space(3)))

__device__ __forceinline__ unsigned short bf16_rne(float x) {
    unsigned u = __builtin_bit_cast(unsigned, x);
    unsigned r = u + 0x7FFFu + ((u >> 16) & 1u);
    return (unsigned short)(r >> 16);
}
__device__ __forceinline__ float bf16_to_f(unsigned short h) {
    unsigned u = ((unsigned)h) << 16;
    return __builtin_bit_cast(float, u);
}

__device__ __forceinline__ float wred(float v)
{
    #pragma unroll
    for (int o = 32; o; o >>= 1) v += __shfl_xor(v, o);
    return v;
}

#define MFMA3(ACC, AH, AL, BH, BL)                                              \
    ACC = __builtin_amdgcn_mfma_f32_16x16x32_bf16(AH, BH, ACC, 0, 0, 0);        \
    ACC = __builtin_amdgcn_mfma_f32_16x16x32_bf16(AL, BH, ACC, 0, 0, 0);        \
    ACC = __builtin_amdgcn_mfma_f32_16x16x32_bf16(AH, BL, ACC, 0, 0, 0);

// ==================================================================
// W (K x N f32) -> Wt_hi/Wt_lo (N x KP bf16), zero-padded.
// ==================================================================
__global__ __launch_bounds__(256)
void split_transpose(const float* __restrict__ W, short* __restrict__ Thi,
                     short* __restrict__ Tlo, int K, int N, int KP)
{
    __shared__ float T[64][68];
    const int t = threadIdx.x;
    const int k0 = blockIdx.x * 64, n0 = blockIdx.y * 64;
    #pragma unroll
    for (int q = 0; q < 4; ++q) {
        const int r = (t >> 4) + q * 16;
        const int c4 = (t & 15) * 4;
        float4 v = make_float4(0.f, 0.f, 0.f, 0.f);
        if (k0 + r < K)
            v = *reinterpret_cast<const float4*>(W + (size_t)(k0 + r) * N + n0 + c4);
        T[r][c4] = v.x; T[r][c4 + 1] = v.y; T[r][c4 + 2] = v.z; T[r][c4 + 3] = v.w;
    }
    __syncthreads();
    #pragma unroll
    for (int q = 0; q < 4; ++q) {
        const int nl = (t >> 4) + q * 16;
        const int kc = (t & 15) * 4;
        short hs[4] __attribute__((aligned(8)));
        short ls[4] __attribute__((aligned(8)));
        #pragma unroll
        for (int i = 0; i < 4; ++i) {
            const float x = T[kc + i][nl];
            const unsigned short hb = bf16_rne(x);
            hs[i] = (short)hb;
            ls[i] = (short)bf16_rne(x - bf16_to_f(hb));
        }
        const size_t o = (size_t)(n0 + nl) * KP + k0 + kc;
        *reinterpret_cast<short4v*>(Thi + o) = *reinterpret_cast<short4v*>(hs);
        *reinterpret_cast<short4v*>(Tlo + o) = *reinterpret_cast<short4v*>(ls);
    }
}

// ==================================================================
// Row-major A (M x K f32) -> A_hi/A_lo (M x KP bf16), zero-padded.
// ==================================================================
__global__ __launch_bounds__(256)
void split_rows(const float* __restrict__ A, short* __restrict__ Hi,
                short* __restrict__ Lo, int M, int K, int KP)
{
    const int gp  = KP >> 3;
    const int idx = blockIdx.x * 256 + threadIdx.x;
    if (idx >= M * gp) return;
    const int row = idx / gp;
    const int g8  = (idx - row * gp) * 8;

    float v[8] __attribute__((aligned(16)));
    const float* src = A + (size_t)row * K + g8;
    if (g8 + 8 <= K) {
        *reinterpret_cast<float4*>(&v[0]) = *reinterpret_cast<const float4*>(src);
        *reinterpret_cast<float4*>(&v[4]) = *reinterpret_cast<const float4*>(src + 4);
    } else {
        #pragma unroll
        for (int i = 0; i < 8; ++i) v[i] = (g8 + i < K) ? src[i] : 0.f;
    }
    short hs[8] __attribute__((aligned(16)));
    short ls[8] __attribute__((aligned(16)));
    #pragma unroll
    for (int i = 0; i < 8; ++i) {
        const unsigned short hb = bf16_rne(v[i]);
        hs[i] = (short)hb;
        ls[i] = (short)bf16_rne(v[i] - bf16_to_f(hb));
    }
    const size_t o = (size_t)row * KP + g8;
    *reinterpret_cast<short8*>(Hi + o) = *reinterpret_cast<short8*>(hs);
    *reinterpret_cast<short8*>(Lo + o) = *reinterpret_cast<short8*>(ls);
}

// ==================================================================
// 96x128 GEMM, pre-split bf16 operands, XCD swizzle. NEW: epilogue
// writes (acc+bias) split to hi/lo bf16 in batch-padded emb layout.
// ==================================================================
#define BM 96
#define BN 128
__global__ __launch_bounds__(256)
void gemm_presplit_sw(const short* __restrict__ Ahg, const short* __restrict__ Alg,
                      const short* __restrict__ Bhg, const short* __restrict__ Blg,
                      const float* __restrict__ bias, short* __restrict__ Chi,
                      short* __restrict__ Clo, int M, int N, int KP,
                      int RPB, int PRB)
{
    __shared__ short Ahi[BM * 32], Alo[BM * 32];
    __shared__ short Bhi[BN * 32], Blo[BN * 32];

    const int tid  = threadIdx.x;
    const int w    = tid >> 6, lane = tid & 63;
    const int wr   = w >> 1,   wc   = w & 1;

    const int nwg  = (int)gridDim.x;
    const int cpx  = nwg >> 3;
    const int bid  = (int)blockIdx.x;
    const int swz  = (bid & 7) * cpx + (bid >> 3);
    const int ncol = N / BN;
    const int col0 = (swz % ncol) * BN;
    const int row0 = (swz / ncol) * BM;

    f32x4 acc[3][4];
    #pragma unroll
    for (int m = 0; m < 3; ++m)
        #pragma unroll
        for (int n = 0; n < 4; ++n)
            acc[m][n] = (f32x4){0.f, 0.f, 0.f, 0.f};

    for (int k0 = 0; k0 < KP; k0 += 32) {
        __syncthreads();
        for (int c = tid; c < (BM * 32) / 8; c += 256) {
            const int r = c >> 2, k8 = (c & 3) * 8;
            const size_t ga = (size_t)(row0 + r) * KP + k0 + k8;
            __builtin_amdgcn_global_load_lds((AS1 void*)(Ahg + ga),
                                             (AS3 void*)(Ahi + c * 8), 16, 0, 0);
            __builtin_amdgcn_global_load_lds((AS1 void*)(Alg + ga),
                                             (AS3 void*)(Alo + c * 8), 16, 0, 0);
        }
        for (int c = tid; c < (BN * 32) / 8; c += 256) {
            const int r = c >> 2, k8 = (c & 3) * 8;
            const size_t gb = (size_t)(col0 + r) * KP + k0 + k8;
            __builtin_amdgcn_global_load_lds((AS1 void*)(Bhg + gb),
                                             (AS3 void*)(Bhi + c * 8), 16, 0, 0);
            __builtin_amdgcn_global_load_lds((AS1 void*)(Blg + gb),
                                             (AS3 void*)(Blo + c * 8), 16, 0, 0);
        }
        __syncthreads();

        short8 ah[3], al[3];
        #pragma unroll
        for (int m = 0; m < 3; ++m) {
            const int r = wr * 48 + m * 16 + (lane & 15);
            const int o = r * 32 + (lane >> 4) * 8;
            ah[m] = *reinterpret_cast<const short8*>(&Ahi[o]);
            al[m] = *reinterpret_cast<const short8*>(&Alo[o]);
        }
        #pragma unroll
        for (int n = 0; n < 4; ++n) {
            const int r = wc * 64 + n * 16 + (lane & 15);
            const int o = r * 32 + (lane >> 4) * 8;
            const short8 bh = *reinterpret_cast<const short8*>(&Bhi[o]);
            const short8 bl = *reinterpret_cast<const short8*>(&Blo[o]);
            #pragma unroll
            for (int m = 0; m < 3; ++m) {
                MFMA3(acc[m][n], ah[m], al[m], bh, bl)
            }
        }
    }

    float bv[4];
    #pragma unroll
    for (int n = 0; n < 4; ++n)
        bv[n] = bias[col0 + wc * 64 + n * 16 + (lane & 15)];
    #pragma unroll
    for (int m = 0; m < 3; ++m)
        #pragma unroll
        for (int j = 0; j < 4; ++j) {
            const int gr = row0 + wr * 48 + m * 16 + (lane >> 4) * 4 + j;
            const int bb = gr / RPB;
            const int rr = gr - bb * RPB;
            const size_t drow = (size_t)bb * PRB + rr;
            const int cb = col0 + wc * 64 + (lane & 15);
            #pragma unroll
            for (int n = 0; n < 4; ++n) {
                const float val = acc[m][n][j] + bv[n];
                const unsigned short hb = bf16_rne(val);
                Chi[drow * N + cb + n * 16] = (short)hb;
                Clo[drow * N + cb + n * 16] = (short)bf16_rne(val - bf16_to_f(hb));
            }
        }
}

// ==================================================================
// Per-batch S = capE @ imgE^T (mode 0, + ||cap||^2 diag) and
// G = imgE @ imgE^T (mode 1) via MFMA on split-bf16 embeddings.
// Grid (NB, 2). Padded rows carry garbage -> only ignored outputs.
// ==================================================================
__global__ __launch_bounds__(256)
void sg_kernel(const short* __restrict__ iHi, const short* __restrict__ iLo,
               const short* __restrict__ cHi, const short* __restrict__ cLo,
               float* __restrict__ S, float* __restrict__ G,
               float* __restrict__ scap)
{
    __shared__ short sIH[PRI * 32], sIL[PRI * 32];   // 3 KB each
    __shared__ short sCH[PRC * 32], sCL[PRC * 32];   // 4 KB each

    const int b    = blockIdx.x;
    const int mode = blockIdx.y;
    const int tid  = threadIdx.x;
    const int w    = tid >> 6, lane = tid & 63;

    f32x4 acc0 = (f32x4){0.f,0.f,0.f,0.f};
    f32x4 acc1 = acc0, acc2 = acc0, accd = acc0;

    for (int k0 = 0; k0 < DEMB; k0 += 32) {
        __syncthreads();
        // stage img tile (both modes): 48 rows x 32k, hi/lo
        if (tid < (PRI * 32) / 8) {
            const int r = tid >> 2, k8 = (tid & 3) * 8;
            const size_t g = (size_t)(b * PRI + r) * DEMB + k0 + k8;
            __builtin_amdgcn_global_load_lds((AS1 void*)(iHi + g),
                                             (AS3 void*)(sIH + tid * 8), 16, 0, 0);
            __builtin_amdgcn_global_load_lds((AS1 void*)(iLo + g),
                                             (AS3 void*)(sIL + tid * 8), 16, 0, 0);
        }
        if (mode == 0) {   // stage cap tile: 64 rows x 32k, hi/lo
            const int r = tid >> 2, k8 = (tid & 3) * 8;
            const size_t g = (size_t)(b * PRC + r) * DEMB + k0 + k8;
            __builtin_amdgcn_global_load_lds((AS1 void*)(cHi + g),
                                             (AS3 void*)(sCH + tid * 8), 16, 0, 0);
            __builtin_amdgcn_global_load_lds((AS1 void*)(cLo + g),
                                             (AS3 void*)(sCL + tid * 8), 16, 0, 0);
        }
        __syncthreads();

        if (mode == 0 || w < 3) {
            const int ao = ((w << 4) + (lane & 15)) * 32 + (lane >> 4) * 8;
            short8 ah, al;
            if (mode == 0) {
                ah = *reinterpret_cast<const short8*>(&sCH[ao]);
                al = *reinterpret_cast<const short8*>(&sCL[ao]);
            } else {
                ah = *reinterpret_cast<const short8*>(&sIH[ao]);
                al = *reinterpret_cast<const short8*>(&sIL[ao]);
            }
            const int bo = (lane & 15) * 32 + (lane >> 4) * 8;
            const short8 b0h = *reinterpret_cast<const short8*>(&sIH[bo]);
            const short8 b0l = *reinterpret_cast<const short8*>(&sIL[bo]);
            const short8 b1h = *reinterpret_cast<const short8*>(&sIH[bo + 512]);
            const short8 b1l = *reinterpret_cast<const short8*>(&sIL[bo + 512]);
            const short8 b2h = *reinterpret_cast<const short8*>(&sIH[bo + 1024]);
            const short8 b2l = *reinterpret_cast<const short8*>(&sIL[bo + 1024]);
            MFMA3(acc0, ah, al, b0h, b0l)
            MFMA3(acc1, ah, al, b1h, b1l)
            MFMA3(acc2, ah, al, b2h, b2l)
            if (mode == 0) {   // self product for ||cap||^2 diag
                MFMA3(accd, ah, al, ah, al)
            }
        }
    }

    const int rloc = (w << 4) + (lane >> 4) * 4;   // + j
    const int cloc = lane & 15;
    if (mode == 0) {
        float* Sb = S + (size_t)b * (PRC * PRI);
        #pragma unroll
        for (int j = 0; j < 4; ++j) {
            Sb[(rloc + j) * PRI + cloc]      = acc0[j];
            Sb[(rloc + j) * PRI + 16 + cloc] = acc1[j];
            Sb[(rloc + j) * PRI + 32 + cloc] = acc2[j];
        }
        #pragma unroll
        for (int j = 0; j < 4; ++j)
            if (cloc == (lane >> 4) * 4 + j)
                scap[b * PRC + (w << 4) + cloc] = accd[j];
    } else if (w < 3) {
        float* Gb = G + (size_t)b * (PRI * PRI);
        #pragma unroll
        for (int j = 0; j < 4; ++j) {
            Gb[(rloc + j) * PRI + cloc]      = acc0[j];
            Gb[(rloc + j) * PRI + 16 + cloc] = acc1[j];
            Gb[(rloc + j) * PRI + 32 + cloc] = acc2[j];
        }
    }
}

// ==================================================================
// Finalize: softmax weights, num = w.s, ||att||^2 = w^T Gn w, cosine,
// masked mean. One block per batch (4 waves x 15 words). Direct store.
// ==================================================================
__global__ __launch_bounds__(256)
void finalize_kernel(const float* __restrict__ S, const float* __restrict__ G,
                     const float* __restrict__ scap, const int* __restrict__ lens,
                     float* __restrict__ out)
{
    __shared__ float sG[36][37];
    __shared__ float sfi[36];
    __shared__ float wsum[4];

    const int b = blockIdx.x;
    const int tid = threadIdx.x, w = tid >> 6, lane = tid & 63;
    const int len = lens[b];
    const float* Gb = G + (size_t)b * (PRI * PRI);
    const float* Sb = S + (size_t)b * (PRC * PRI);

    if (tid < NR) sfi[tid] = rsqrtf(Gb[tid * PRI + tid] + 1e-12f);
    __syncthreads();
    for (int t = tid; t < NR * NR; t += 256) {
        const int r = t / 36, c = t - r * 36;
        sG[r][c] = Gb[r * PRI + c] * sfi[r] * sfi[c];
    }
    __syncthreads();

    float wacc = 0.f;
    for (int l = w; l < NL; l += 4) {
        const float sc2 = scap[b * PRC + l];
        const float fc  = rsqrtf(sc2 + 1e-12f);
        const float sv  = (lane < NR) ? Sb[l * PRI + lane] * fc * sfi[lane] : -1e30f;
        float m = sv;
        #pragma unroll
        for (int o = 32; o; o >>= 1) m = fmaxf(m, __shfl_xor(m, o));
        const float e = (lane < NR) ? __expf(9.f * (sv - m)) : 0.f;
        float num = 0.f, aq = 0.f;
        if (lane < NR) {
            float q = 0.f;
            // q = (Gn e)_lane via broadcast of e across lanes
            #pragma unroll
            for (int rp = 0; rp < NR; ++rp) {
                const float erp = __shfl(e, rp);
                q = fmaf(sG[lane][rp], erp, q);
            }
            num = e * sv;
            aq  = e * q;
        }
        num = wred(num);
        aq  = wred(aq);
        if (lane == 0 && l < len) {
            const float nu   = fmaxf(sqrtf(sc2) * fc, 1e-8f);
            const float natt = fmaxf(sqrtf(aq), 1e-8f);
            wacc += num / (nu * natt);
        }
    }
    if (lane == 0) wsum[w] = wacc;
    __syncthreads();
    if (tid == 0)
        out[b] = (wsum[0] + wsum[1] + wsum[2] + wsum[3]) / (float)len;
}

// ==================================================================
// Fallback kernels (mid-ws and small-ws tiers) — unchanged from r5/r7
// ==================================================================
__global__ __launch_bounds__(256)
void gemm_asplit(const float* __restrict__ A, const short* __restrict__ Bthi,
                 const short* __restrict__ Btlo, const float* __restrict__ bias,
                 float* __restrict__ C, int M, int N, int K, int KP)
{
    __shared__ short Ahi[128 * 32], Alo[128 * 32];
    __shared__ short Bhi[128 * 32], Blo[128 * 32];

    const int tid  = threadIdx.x;
    const int w    = tid >> 6, lane = tid & 63;
    const int wr   = w >> 1,   wc   = w & 1;
    const int row0 = blockIdx.y * 128, col0 = blockIdx.x * 128;

    f32x4 acc[4][4];
    #pragma unroll
    for (int m = 0; m < 4; ++m)
        #pragma unroll
        for (int n = 0; n < 4; ++n)
            acc[m][n] = (f32x4){0.f, 0.f, 0.f, 0.f};

    for (int k0 = 0; k0 < KP; k0 += 32) {
        __syncthreads();
        #pragma unroll
        for (int h = 0; h < 2; ++h) {
            const int c = tid + h * 256;
            const int r = c >> 2;
            const int ke = (c & 3) * 8;
            const int gk = k0 + ke;
            const float* src = A + (size_t)(row0 + r) * K + gk;
            float v[8] __attribute__((aligned(16)));
            if (gk + 8 <= K) {
                *reinterpret_cast<float4*>(&v[0]) = *reinterpret_cast<const float4*>(src);
                *reinterpret_cast<float4*>(&v[4]) = *reinterpret_cast<const float4*>(src + 4);
            } else {
                #pragma unroll
                for (int i = 0; i < 8; ++i)
                    v[i] = (gk + i < K) ? src[i] : 0.f;
            }
            short hs[8] __attribute__((aligned(16)));
            short ls[8] __attribute__((aligned(16)));
            #pragma unroll
            for (int i = 0; i < 8; ++i) {
                const unsigned short hb = bf16_rne(v[i]);
                hs[i] = (short)hb;
                ls[i] = (short)bf16_rne(v[i] - bf16_to_f(hb));
            }
            *reinterpret_cast<short8*>(&Ahi[c * 8]) = *reinterpret_cast<short8*>(hs);
            *reinterpret_cast<short8*>(&Alo[c * 8]) = *reinterpret_cast<short8*>(ls);
        }
        #pragma unroll
        for (int j = 0; j < 2; ++j) {
            const int s = w * 2 + j;
            const int n = 16 * s + (lane >> 2);
            const size_t go = (size_t)(col0 + n) * KP + k0 + (lane & 3) * 8;
            __builtin_amdgcn_global_load_lds((AS1 void*)(Bthi + go),
                                             (AS3 void*)(Bhi + s * 512), 16, 0, 0);
            __builtin_amdgcn_global_load_lds((AS1 void*)(Btlo + go),
                                             (AS3 void*)(Blo + s * 512), 16, 0, 0);
        }
        __syncthreads();

        short8 ah[4], al[4];
        #pragma unroll
        for (int m = 0; m < 4; ++m) {
            const int r = wr * 64 + m * 16 + (lane & 15);
            const int o = r * 32 + (lane >> 4) * 8;
            ah[m] = *reinterpret_cast<const short8*>(&Ahi[o]);
            al[m] = *reinterpret_cast<const short8*>(&Alo[o]);
        }
        #pragma unroll
        for (int n = 0; n < 4; ++n) {
            const int r = wc * 64 + n * 16 + (lane & 15);
            const int o = r * 32 + (lane >> 4) * 8;
            const short8 bh = *reinterpret_cast<const short8*>(&Bhi[o]);
            const short8 bl = *reinterpret_cast<const short8*>(&Blo[o]);
            #pragma unroll
            for (int m = 0; m < 4; ++m) {
                MFMA3(acc[m][n], ah[m], al[m], bh, bl)
            }
        }
    }

    float bv[4];
    #pragma unroll
    for (int n = 0; n < 4; ++n)
        bv[n] = bias[col0 + wc * 64 + n * 16 + (lane & 15)];
    #pragma unroll
    for (int m = 0; m < 4; ++m)
        #pragma unroll
        for (int j = 0; j < 4; ++j) {
            const int gr = row0 + wr * 64 + m * 16 + (lane >> 4) * 4 + j;
            float* dst = C + (size_t)gr * N + col0 + wc * 64 + (lane & 15);
            #pragma unroll
            for (int n = 0; n < 4; ++n)
                dst[n * 16] = acc[m][n][j] + bv[n];
        }
}

__global__ __launch_bounds__(256)
void sgemm_bias(const float* __restrict__ A, const float* __restrict__ Bm,
                const float* __restrict__ bias, float* __restrict__ C,
                int M, int N, int K)
{
    __shared__ float As[16][136];
    __shared__ float Bs[16][136];
    const int tid = threadIdx.x;
    const int tx  = tid & 15;
    const int ty  = tid >> 4;
    const int row0 = blockIdx.y * 128;
    const int col0 = blockIdx.x * 128;
    const int ar = tid >> 2;
    const int ac = (tid & 3) << 2;
    const int br = tid >> 5;
    const int bc = (tid & 31) << 2;
    float acc[8][8];
    #pragma unroll
    for (int i = 0; i < 8; ++i)
        #pragma unroll
        for (int j = 0; j < 8; ++j) acc[i][j] = 0.f;
    for (int k0 = 0; k0 < K; k0 += 16) {
        __syncthreads();
        #pragma unroll
        for (int h = 0; h < 2; ++h) {
            const int r = ar + h * 64;
            const float* src = A + (size_t)(row0 + r) * K + k0 + ac;
            float4 v;
            if (k0 + ac + 4 <= K) {
                v = *reinterpret_cast<const float4*>(src);
            } else {
                v.x = (k0 + ac + 0 < K) ? src[0] : 0.f;
                v.y = (k0 + ac + 1 < K) ? src[1] : 0.f;
                v.z = (k0 + ac + 2 < K) ? src[2] : 0.f;
                v.w = (k0 + ac + 3 < K) ? src[3] : 0.f;
            }
            As[ac + 0][r] = v.x; As[ac + 1][r] = v.y;
            As[ac + 2][r] = v.z; As[ac + 3][r] = v.w;
        }
        #pragma unroll
        for (int h = 0; h < 2; ++h) {
            const int r = br + h * 8;
            float4 v = make_float4(0.f, 0.f, 0.f, 0.f);
            if (k0 + r < K)
                v = *reinterpret_cast<const float4*>(Bm + (size_t)(k0 + r) * N + col0 + bc);
            *reinterpret_cast<float4*>(&Bs[r][bc]) = v;
        }
        __syncthreads();
        #pragma unroll
        for (int kk = 0; kk < 16; ++kk) {
            float a[8], b[8];
            *reinterpret_cast<float4*>(&a[0]) = *reinterpret_cast<const float4*>(&As[kk][ty * 8]);
            *reinterpret_cast<float4*>(&a[4]) = *reinterpret_cast<const float4*>(&As[kk][ty * 8 + 4]);
            *reinterpret_cast<float4*>(&b[0]) = *reinterpret_cast<const float4*>(&Bs[kk][tx * 8]);
            *reinterpret_cast<float4*>(&b[4]) = *reinterpret_cast<const float4*>(&Bs[kk][tx * 8 + 4]);
            #pragma unroll
            for (int i = 0; i < 8; ++i)
                #pragma unroll
                for (int j = 0; j < 8; ++j)
                    acc[i][j] = fmaf(a[i], b[j], acc[i][j]);
        }
    }
    float bvv[8];
    *reinterpret_cast<float4*>(&bvv[0]) = *reinterpret_cast<const float4*>(bias + col0 + tx * 8);
    *reinterpret_cast<float4*>(&bvv[4]) = *reinterpret_cast<const float4*>(bias + col0 + tx * 8 + 4);
    #pragma unroll
    for (int i = 0; i < 8; ++i) {
        float* dst = C + (size_t)(row0 + ty * 8 + i) * N + col0 + tx * 8;
        float4 o0 = make_float4(acc[i][0] + bvv[0], acc[i][1] + bvv[1],
                                acc[i][2] + bvv[2], acc[i][3] + bvv[3]);
        float4 o1 = make_float4(acc[i][4] + bvv[4], acc[i][5] + bvv[5],
                                acc[i][6] + bvv[6], acc[i][7] + bvv[7]);
        *reinterpret_cast<float4*>(dst)     = o0;
        *reinterpret_cast<float4*>(dst + 4) = o1;
    }
}

__global__ __launch_bounds__(256)
void gram_kernel2(const float* __restrict__ img, float* __restrict__ G)
{
    const int b = blockIdx.x;
    const int w = threadIdx.x >> 6, lane = threadIdx.x & 63;
    const int r = blockIdx.y * 4 + w;
    const float* X = img + (size_t)b * NR * DEMB;
    float* Gb = G + (size_t)b * NR * NR;

    float c[16];
    #pragma unroll
    for (int j = 0; j < 16; ++j) c[j] = X[(size_t)r * DEMB + j * 64 + lane];
    for (int rp = 0; rp < NR; ++rp) {
        float p = 0.f;
        #pragma unroll
        for (int j = 0; j < 16; ++j)
            p = fmaf(c[j], X[(size_t)rp * DEMB + j * 64 + lane], p);
        p = wred(p);
        if (lane == 0) Gb[r * NR + rp] = p;
    }
}

#define CH 6
__global__ __launch_bounds__(256)
void scan_attn3(const float* __restrict__ img, const float* __restrict__ cap,
                const float* __restrict__ G, const int* __restrict__ lens,
                float* __restrict__ out)
{
    __shared__ float simg[CH * 1024];
    __shared__ float sS[15][37];
    __shared__ float sE[15][37];
    __shared__ float sG[36][37];
    __shared__ float sfi[36];
    __shared__ float scap[15];
    __shared__ float wsum[4];

    const int g = blockIdx.x;
    const int b = blockIdx.y;
    const int tid = threadIdx.x, w = tid >> 6, lane = tid & 63;
    const int len = lens[b];
    const int l0 = g * 15;
    const float* imgb = img + (size_t)b * NR * DEMB;
    const float* capb = cap + (size_t)b * NL * DEMB;
    const float* Gb   = G + (size_t)b * (NR * NR);

    if (tid < NR) sfi[tid] = rsqrtf(Gb[tid * NR + tid] + 1e-12f);
    __syncthreads();
    for (int t = tid; t < NR * NR; t += 256) {
        const int r = t / 36, c = t - r * 36;
        sG[r][c] = Gb[t] * sfi[r] * sfi[c];
    }

    for (int rc = 0; rc < 6; ++rc) {
        __syncthreads();
        {
            const float4* src = reinterpret_cast<const float4*>(imgb + (size_t)rc * CH * DEMB);
            float4* dst = reinterpret_cast<float4*>(simg);
            #pragma unroll
            for (int t = 0; t < 6; ++t) dst[tid + t * 256] = src[tid + t * 256];
        }
        __syncthreads();
        for (int i = w; i < 15; i += 4) {
            const int l = l0 + i;
            float c[16];
            #pragma unroll
            for (int j = 0; j < 16; ++j) c[j] = capb[(size_t)l * DEMB + j * 64 + lane];
            if (rc == 0) {
                float s2 = 0.f;
                #pragma unroll
                for (int j = 0; j < 16; ++j) s2 = fmaf(c[j], c[j], s2);
                s2 = wred(s2);
                if (lane == 0) scap[i] = s2;
            }
            #pragma unroll
            for (int r = 0; r < CH; ++r) {
                float p = 0.f;
                #pragma unroll
                for (int j = 0; j < 16; ++j)
                    p = fmaf(c[j], simg[r * 1024 + j * 64 + lane], p);
                p = wred(p);
                if (lane == 0) sS[i][rc * CH + r] = p;
            }
        }
    }

    float wacc = 0.f;
    for (int i = w; i < 15; i += 4) {
        const int l = l0 + i;
        const float fc = rsqrtf(scap[i] + 1e-12f);
        const float sv = (lane < NR) ? sS[i][lane] * fc * sfi[lane] : -1e30f;
        float m = sv;
        #pragma unroll
        for (int o = 32; o; o >>= 1) m = fmaxf(m, __shfl_xor(m, o));
        const float e = (lane < NR) ? __expf(9.f * (sv - m)) : 0.f;
        if (lane < NR) sE[i][lane] = e;
        float num = 0.f, aq = 0.f;
        if (lane < NR) {
            float q = 0.f;
            #pragma unroll
            for (int rp = 0; rp < NR; ++rp)
                q = fmaf(sG[lane][rp], sE[i][rp], q);
            num = e * sv;
            aq  = e * q;
        }
        num = wred(num);
        aq  = wred(aq);
        if (lane == 0 && l < len) {
            const float nu   = fmaxf(sqrtf(scap[i]) * fc, 1e-8f);
            const float natt = fmaxf(sqrtf(aq), 1e-8f);
            wacc += num / (nu * natt);
        }
    }
    if (lane == 0) wsum[w] = wacc;
    __syncthreads();
    if (tid == 0) {
        const float s = wsum[0] + wsum[1] + wsum[2] + wsum[3];
        atomicAdd(out + b, s / (float)len);
    }
}

// ==================================================================
extern "C" void kernel_launch(void* const* d_in, const int* in_sizes, int n_in,
                              void* d_out, int out_size, void* d_ws, size_t ws_size,
                              hipStream_t stream)
{
    const float* images   = (const float*)d_in[0];
    const float* captions = (const float*)d_in[1];
    const int*   lens     = (const int*)  d_in[2];
    const float* W_img    = (const float*)d_in[3];
    const float* b_img    = (const float*)d_in[4];
    const float* W_txt    = (const float*)d_in[5];
    const float* b_txt    = (const float*)d_in[6];
    float*       out      = (float*)d_out;

    const size_t AIT  = (size_t)NB * NR * DIMG * 2;    // 37.75 MB per half
    const size_t ACT  = (size_t)NB * NL * KPC * 2;     // 9.83 MB per half
    const size_t WIT  = (size_t)DEMB * DIMG * 2;       // 4 MiB per half
    const size_t WTT  = (size_t)DEMB * KPC * 2;
    const size_t IET  = (size_t)NB * PRI * DEMB * 2;   // 25.17 MB per half
    const size_t CET  = (size_t)NB * PRC * DEMB * 2;   // 33.55 MB per half
    const size_t S_B  = (size_t)NB * PRC * PRI * 4;
    const size_t G_B2 = (size_t)NB * PRI * PRI * 4;
    const size_t SC_B = (size_t)NB * PRC * 4;

    char* base = (char*)d_ws;
    // ---- new-path layout ----
    size_t o = 0;
    short* AimgHi = (short*)(base + o); o += AIT;
    short* AimgLo = (short*)(base + o); o += AIT;
    short* AcapHi = (short*)(base + o); o += ACT;
    short* AcapLo = (short*)(base + o); o += ACT;
    short* WimgT_hi = (short*)(base + o); o += WIT;
    short* WimgT_lo = (short*)(base + o); o += WIT;
    short* WtxtT_hi = (short*)(base + o); o += WTT;
    short* WtxtT_lo = (short*)(base + o); o += WTT;
    short* imgE_hi  = (short*)(base + o); o += IET;
    short* imgE_lo  = (short*)(base + o); o += IET;
    float* Sm   = (float*)(base + o); o += S_B;
    float* Gm2  = (float*)(base + o); o += G_B2;
    float* scap = (float*)(base + o); o += SC_B;
    const size_t NEED_NEW = o;                         // ~160.8 MB
    // capE overlays the (spent-after-img-GEMM) Aimg region
    short* capE_hi = (short*)(base);
    short* capE_lo = (short*)(base + CET);

    if (ws_size >= NEED_NEW) {
        split_transpose<<<dim3(DIMG / 64, DEMB / 64), 256, 0, stream>>>(
            W_img, WimgT_hi, WimgT_lo, DIMG, DEMB, DIMG);
        split_transpose<<<dim3(KPC / 64, DEMB / 64), 256, 0, stream>>>(
            W_txt, WtxtT_hi, WtxtT_lo, DWRD, DEMB, KPC);
        split_rows<<<(NB * NR * (DIMG / 8) + 255) / 256, 256, 0, stream>>>(
            images, AimgHi, AimgLo, NB * NR, DIMG, DIMG);
        split_rows<<<(NB * NL * (KPC / 8) + 255) / 256, 256, 0, stream>>>(
            captions, AcapHi, AcapLo, NB * NL, DWRD, KPC);

        gemm_presplit_sw<<<(DEMB / BN) * ((NB * NR) / BM), 256, 0, stream>>>(
            AimgHi, AimgLo, WimgT_hi, WimgT_lo, b_img, imgE_hi, imgE_lo,
            NB * NR, DEMB, DIMG, NR, PRI);
        gemm_presplit_sw<<<(DEMB / BN) * ((NB * NL) / BM), 256, 0, stream>>>(
            AcapHi, AcapLo, WtxtT_hi, WtxtT_lo, b_txt, capE_hi, capE_lo,
            NB * NL, DEMB, KPC, NL, PRC);

        sg_kernel<<<dim3(NB, 2), 256, 0, stream>>>(
            imgE_hi, imgE_lo, capE_hi, capE_lo, Sm, Gm2, scap);
        finalize_kernel<<<NB, 256, 0, stream>>>(Sm, Gm2, scap, lens, out);
        return;
    }

    // ---- fallback layouts (f32 embs at base, as in r5/r7) ----
    const size_t EMB = (size_t)(NB * NR + NB * NL) * DEMB * 4;
    float* img_embs = (float*)base;
    float* cap_embs = (float*)(base + (size_t)NB * NR * DEMB * 4);
    size_t o2 = EMB;
    short* FWih = (short*)(base + o2); o2 += WIT;
    short* FWil = (short*)(base + o2); o2 += WIT;
    short* FWth = (short*)(base + o2); o2 += WTT;
    short* FWtl = (short*)(base + o2); o2 += WTT;
    const size_t NEED1 = o2;
    float* Gm1 = (float*)(base + EMB);   // overlays spent W region post-GEMM

    if (ws_size >= NEED1) {
        split_transpose<<<dim3(DIMG / 64, DEMB / 64), 256, 0, stream>>>(
            W_img, FWih, FWil, DIMG, DEMB, DIMG);
        split_transpose<<<dim3(KPC / 64, DEMB / 64), 256, 0, stream>>>(
            W_txt, FWth, FWtl, DWRD, DEMB, KPC);
        gemm_asplit<<<dim3(DEMB / 128, (NB * NR) / 128), 256, 0, stream>>>(
            images, FWih, FWil, b_img, img_embs, NB * NR, DEMB, DIMG, DIMG);
        gemm_asplit<<<dim3(DEMB / 128, (NB * NL) / 128), 256, 0, stream>>>(
            captions, FWth, FWtl, b_txt, cap_embs, NB * NL, DEMB, DWRD, KPC);
    } else {
        sgemm_bias<<<dim3(DEMB / 128, (NB * NR) / 128), 256, 0, stream>>>(
            images, W_img, b_img, img_embs, NB * NR, DEMB, DIMG);
        sgemm_bias<<<dim3(DEMB / 128, (NB * NL) / 128), 256, 0, stream>>>(
            captions, W_txt, b_txt, cap_embs, NB * NL, DEMB, DWRD);
    }

    gram_kernel2<<<dim3(NB, 9), 256, 0, stream>>>(img_embs, Gm1);
    hipMemsetAsync(d_out, 0, NB * sizeof(float), stream);
    scan_attn3<<<dim3(4, NB), 256, 0, stream>>>(img_embs, cap_embs, Gm1, lens, out);
}